// Round 4
// baseline (239.108 us; speedup 1.0000x reference)
//
#include <hip/hip_runtime.h>
#include <math.h>

#define B_    2
#define SEQ_  2048
#define D_    256
#define H_    8
#define DK_   32
#define L_    2
#define DFF_  1024

#define TD_CUT 44.0f

typedef short  bf16x8 __attribute__((ext_vector_type(8)));
typedef float  f32x4  __attribute__((ext_vector_type(4)));

__device__ __forceinline__ int compute_kcut(float tdv) {
    int kcut = SEQ_;
    if (tdv > 1e-9f) {
        float kc = TD_CUT / tdv;
        kcut = (kc >= (float)SEQ_) ? SEQ_ : ((int)kc + 1);
    }
    int kcr = (kcut + 63) & ~63;          // 64-granular: whole K-tiles
    if (kcr > SEQ_) kcr = SEQ_;
    return kcr;
}

__device__ __forceinline__ unsigned short f2bf(float f) {
    unsigned int u = __float_as_uint(f);
    unsigned int r = u + 0x7FFFu + ((u >> 16) & 1u);   // RNE
    return (unsigned short)(r >> 16);
}
__device__ __forceinline__ float bf2f(unsigned short u) {
    return __uint_as_float(((unsigned int)u) << 16);
}
__device__ __forceinline__ float bflo(unsigned int u) {
    return __uint_as_float(u << 16);
}
__device__ __forceinline__ float bfhi(unsigned int u) {
    return __uint_as_float(u & 0xFFFF0000u);
}

__device__ __forceinline__ void gload_lds16(const unsigned short* g, unsigned short* l) {
    __builtin_amdgcn_global_load_lds(
        (const __attribute__((address_space(1))) unsigned int*)(const unsigned int*)g,
        (__attribute__((address_space(3))) unsigned int*)(unsigned int*)l,
        16, 0, 0);
}

// ---------------------------------------------------------------------------
// Kernel 1: prep = weight cvt (blocks 0..767) + conv/pe/hts0 (blocks 768..895).
// ---------------------------------------------------------------------------
__global__ __launch_bounds__(256) void prep_kernel(
    const float* __restrict__ x, const float* __restrict__ w,
    const float* __restrict__ cb, const float* __restrict__ bg,
    const float* __restrict__ bb, const float* __restrict__ pe,
    float* __restrict__ h, unsigned short* __restrict__ hbf,
    const float* __restrict__ p0, const float* __restrict__ p1,
    const float* __restrict__ p2, const float* __restrict__ p3,
    const float* __restrict__ p4, const float* __restrict__ p5,
    unsigned short* __restrict__ q0, unsigned short* __restrict__ q1,
    unsigned short* __restrict__ q2, unsigned short* __restrict__ q3,
    unsigned short* __restrict__ q4, unsigned short* __restrict__ q5,
    float* __restrict__ hts0, float* __restrict__ hts1)
{
    int bid = blockIdx.x;
    if (bid < 768) {                              // ---- cvt path
        int t = bid * 256 + threadIdx.x;
        const float* src; unsigned short* dst; int base;
        if (t < 65536) {
            int a = t >> 14;
            src = a == 0 ? p0 : a == 1 ? p1 : a == 2 ? p2 : p3;
            dst = a == 0 ? q0 : a == 1 ? q1 : a == 2 ? q2 : q3;
            base = (t & 16383) * 8;
        } else {
            int u = t - 65536;
            int a = u >> 16;
            src = a ? p5 : p4;
            dst = a ? q5 : q4;
            base = (u & 65535) * 8;
        }
        float4 v0 = *(const float4*)(src + base);
        float4 v1 = *(const float4*)(src + base + 4);
        bf16x8 o;
        o[0] = (short)f2bf(v0.x); o[1] = (short)f2bf(v0.y);
        o[2] = (short)f2bf(v0.z); o[3] = (short)f2bf(v0.w);
        o[4] = (short)f2bf(v1.x); o[5] = (short)f2bf(v1.y);
        o[6] = (short)f2bf(v1.z); o[7] = (short)f2bf(v1.w);
        *(bf16x8*)(dst + base) = o;
        return;
    }
    // ---- conv path: block = (b, tile of 32 rows); thread = column d
    int bid2 = bid - 768;                         // 0..127
    int b    = bid2 >> 6;
    int tile = bid2 & 63;
    int d    = threadIdx.x;

    hts1[bid2 * 256 + d] = 0.f;

    const float* xp = x + b * SEQ_;
    float w0 = w[d * 3 + 0], w1v = w[d * 3 + 1], w2v = w[d * 3 + 2];
    float gg  = rsqrtf(1.f + 1e-5f) * bg[d];
    float cbd = cb[d], bbd = bb[d];

    int s0 = tile * 32;
    float xm1 = (s0 > 0) ? xp[s0 - 1] : 0.f;
    float x0v = xp[s0];
    float hsum = 0.f;
#pragma unroll 4
    for (int r = 0; r < 32; ++r) {
        int s = s0 + r;
        float xp1 = (s < SEQ_ - 1) ? xp[s + 1] : 0.f;
        float acc = xm1 * w0 + x0v * w1v + xp1 * w2v + cbd;
        acc = acc * gg + bbd;
        acc = fmaxf(acc, 0.f);
        float v = acc + pe[s * D_ + d];
        size_t idx = ((size_t)(b * SEQ_ + s)) * D_ + d;
        h[idx] = v;
        unsigned short ub = f2bf(v);
        hbf[idx] = ub;
        hsum += bf2f(ub);
        xm1 = x0v; x0v = xp1;
    }
    hts0[(b * 64 + tile) * 256 + d] = hsum;
}

// ---------------------------------------------------------------------------
// Kernel 2: q/k/v GEMM (bf16 in/out), BK=64 double-buffered pipeline.
// z==3 slice: vtail precompute — vts_g[b][h][32] from hts suffix-sum . Wv.
// K/V blocks (z==1,2) with rows >= kcut exit immediately.
// ---------------------------------------------------------------------------
__global__ __launch_bounds__(256) void gemm_qkv(
    const unsigned short* __restrict__ A,
    const unsigned short* __restrict__ W0, const unsigned short* __restrict__ W1,
    const unsigned short* __restrict__ W2,
    const float* __restrict__ b0, const float* __restrict__ b1,
    const float* __restrict__ b2,
    unsigned short* __restrict__ O0, unsigned short* __restrict__ O1,
    unsigned short* __restrict__ O2,
    const float* __restrict__ td_l,
    const float* __restrict__ hts_l, float* __restrict__ vts_g,
    int M, int N, int K)
{
    __shared__ unsigned short As[2][2][2048];     // [buf][k-slab][64x32]
    __shared__ unsigned short Bs[2][2][2048];
    __shared__ float hsc[256];

    int z = blockIdx.z;
    int tid  = threadIdx.x;

    if (z == 3) {                                 // ---- vtail path
        if (blockIdx.x != 0 || blockIdx.y >= 16) return;
        int hh = blockIdx.y & 7;
        int b  = blockIdx.y >> 3;
        int kcr = compute_kcut(td_l[hh]);
        if (kcr >= SEQ_) return;                  // no tail needed
        int tcut = kcr >> 5;                      // 32-row tile units (even)
        // Phase A: masked suffix column-sum over 64 tiles (fully unrolled)
        const float* hb = hts_l + (size_t)b * 64 * 256 + tid;
        float s = 0.f;
#pragma unroll
        for (int t = 0; t < 64; ++t) {
            float v = hb[t * 256];
            s += (t >= tcut) ? v : 0.f;
        }
        hsc[tid] = s;
        __syncthreads();
        // Phase B: vts[j] = hsc . Wv[hh*32+j] + (SEQ-kcr)*vb
        int j = tid >> 3, e = tid & 7;
        const unsigned short* wrow = W2 + (size_t)(hh * 32 + j) * 256 + e * 32;
        float dot = 0.f;
#pragma unroll
        for (int i = 0; i < 4; ++i) {
            bf16x8 w8 = *(const bf16x8*)(wrow + i * 8);
#pragma unroll
            for (int t2 = 0; t2 < 8; ++t2)
                dot += hsc[e * 32 + i * 8 + t2] * bf2f((unsigned short)w8[t2]);
        }
        dot += __shfl_xor(dot, 1);
        dot += __shfl_xor(dot, 2);
        dot += __shfl_xor(dot, 4);
        if (e == 0)
            vts_g[(b * H_ + hh) * 32 + j] = dot + (float)(SEQ_ - kcr) * b2[hh * 32 + j];
        return;
    }

    int bm = blockIdx.y * 64, bn = blockIdx.x * 64;
    if (z > 0) {
        float tdmin = td_l[0];
#pragma unroll
        for (int i = 1; i < H_; ++i) tdmin = fminf(tdmin, td_l[i]);
        if ((bm & (SEQ_ - 1)) >= compute_kcut(tdmin)) return;   // block-uniform
    }
    const unsigned short* W = (z == 0) ? W0 : (z == 1) ? W1 : W2;
    const float* bias = (z == 0) ? b0 : (z == 1) ? b1 : b2;
    unsigned short* C = (z == 0) ? O0 : (z == 1) ? O1 : O2;

    int wave = tid >> 6, lane = tid & 63;
    int wm = (wave & 1) * 32, wn = (wave >> 1) * 32;

    int sr  = tid >> 2;
    int scb = (tid & 3) ^ ((sr >> 1) & 3);
    const unsigned short* aG = A + (size_t)(bm + sr) * K + scb * 8;
    const unsigned short* wG = W + (size_t)(bn + sr) * K + scb * 8;

    int fr = lane & 15;
    int kb = lane >> 4;
    int cbo = (kb ^ ((fr >> 1) & 3)) * 8;
    int oA0 = (wm + fr) * 32 + cbo;
    int oA1 = (wm + 16 + fr) * 32 + cbo;
    int oB0 = (wn + fr) * 32 + cbo;
    int oB1 = (wn + 16 + fr) * 32 + cbo;

    f32x4 acc[2][2];
#pragma unroll
    for (int i = 0; i < 2; ++i)
#pragma unroll
        for (int j = 0; j < 2; ++j) acc[i][j] = (f32x4){0.f, 0.f, 0.f, 0.f};

    auto stage = [&](int s, int dd) {
        gload_lds16(aG + s * 64,      &As[dd][0][tid * 8]);
        gload_lds16(aG + s * 64 + 32, &As[dd][1][tid * 8]);
        gload_lds16(wG + s * 64,      &Bs[dd][0][tid * 8]);
        gload_lds16(wG + s * 64 + 32, &Bs[dd][1][tid * 8]);
    };

    int nst = K >> 6;                              // 4 steps (BK=64)
    stage(0, 0);
    __syncthreads();
    for (int s = 0; s < nst; ++s) {
        int dd = s & 1;
        if (s + 1 < nst) stage(s + 1, dd ^ 1);
#pragma unroll
        for (int kk = 0; kk < 2; ++kk) {
            bf16x8 a0f = *(const bf16x8*)&As[dd][kk][oA0];
            bf16x8 a1f = *(const bf16x8*)&As[dd][kk][oA1];
            bf16x8 b0f = *(const bf16x8*)&Bs[dd][kk][oB0];
            bf16x8 b1f = *(const bf16x8*)&Bs[dd][kk][oB1];
            acc[0][0] = __builtin_amdgcn_mfma_f32_16x16x32_bf16(a0f, b0f, acc[0][0], 0, 0, 0);
            acc[0][1] = __builtin_amdgcn_mfma_f32_16x16x32_bf16(a0f, b1f, acc[0][1], 0, 0, 0);
            acc[1][0] = __builtin_amdgcn_mfma_f32_16x16x32_bf16(a1f, b0f, acc[1][0], 0, 0, 0);
            acc[1][1] = __builtin_amdgcn_mfma_f32_16x16x32_bf16(a1f, b1f, acc[1][1], 0, 0, 0);
        }
        __syncthreads();
    }

    int crow = (lane >> 4) * 4;
    int ccol = lane & 15;
#pragma unroll
    for (int j = 0; j < 2; ++j) {
        float bj = bias[bn + wn + j * 16 + ccol];
#pragma unroll
        for (int i = 0; i < 2; ++i) {
#pragma unroll
            for (int r = 0; r < 4; ++r) {
                float v = acc[i][j][r] + bj;
                C[(size_t)(bm + wm + i * 16 + crow + r) * N + bn + wn + j * 16 + ccol] = f2bf(v);
            }
        }
    }
}

// ---------------------------------------------------------------------------
// Kernel 3: decay-truncated attention, one thread = one q-row.
// All 64 live keys per tile staged in LDS; lanes walk keys in lockstep
// (broadcast reads, no conflicts). Softmax reference point fixed at 0
// (tail guarantees m>=0; scores are O(5) — no overflow), so: single pass,
// no max scan, no score storage, no merge. Tail: l += SEQ-kcr,
// O += 0.5*vts (precomputed by gemm z==3).
// ---------------------------------------------------------------------------
__global__ __launch_bounds__(128) void attn_kernel(
    const unsigned short* __restrict__ q, const unsigned short* __restrict__ k,
    const unsigned short* __restrict__ v, const float* __restrict__ vts_g,
    unsigned short* __restrict__ ctxbf,
    const float* __restrict__ scale_p, const float* __restrict__ td_l)
{
    int b = blockIdx.z, hh = blockIdx.y;
    int tid = threadIdx.x;
    int qrow = blockIdx.x * 128 + tid;

    float sc  = 0.17677669529663687f * scale_p[0];
    float tdv = td_l[hh];
    int kcr = compute_kcut(tdv);                  // block-uniform, 64-granular
    int ntiles = kcr >> 6;

    __shared__ float kt[64][36];
    __shared__ float vt[64][36];
    __shared__ float dec_s[64];
    __shared__ float vts_s[32];

    if (tid < 32) vts_s[tid] = vts_g[(b * H_ + hh) * 32 + tid];

    const unsigned short* qptr = q + ((size_t)(b * SEQ_ + qrow)) * D_ + hh * DK_;
    float qreg[32];
#pragma unroll
    for (int j = 0; j < 4; ++j) {
        uint4 u = ((const uint4*)qptr)[j];
        qreg[j*8+0] = bflo(u.x); qreg[j*8+1] = bfhi(u.x);
        qreg[j*8+2] = bflo(u.y); qreg[j*8+3] = bfhi(u.y);
        qreg[j*8+4] = bflo(u.z); qreg[j*8+5] = bfhi(u.z);
        qreg[j*8+6] = bflo(u.w); qreg[j*8+7] = bfhi(u.w);
    }

    float O[32];
#pragma unroll
    for (int d = 0; d < 32; ++d) O[d] = 0.f;
    float l = 0.f;

    int sr = tid >> 1;                            // staged row 0..63
    int shf = (tid & 1) * 16;                     // col half

    for (int t = 0; t < ntiles; ++t) {
        int k0 = t * 64;
        if (t > 0) __syncthreads();               // WAR on kt/vt
        {
            size_t goff = ((size_t)(b * SEQ_ + k0 + sr)) * D_ + hh * DK_ + shf;
            uint4 ka = *(const uint4*)(k + goff);
            uint4 kb4 = *(const uint4*)(k + goff + 8);
            uint4 va = *(const uint4*)(v + goff);
            uint4 vb4 = *(const uint4*)(v + goff + 8);
            *(float4*)&kt[sr][shf + 0]  = make_float4(bflo(ka.x), bfhi(ka.x), bflo(ka.y), bfhi(ka.y));
            *(float4*)&kt[sr][shf + 4]  = make_float4(bflo(ka.z), bfhi(ka.z), bflo(ka.w), bfhi(ka.w));
            *(float4*)&kt[sr][shf + 8]  = make_float4(bflo(kb4.x), bfhi(kb4.x), bflo(kb4.y), bfhi(kb4.y));
            *(float4*)&kt[sr][shf + 12] = make_float4(bflo(kb4.z), bfhi(kb4.z), bflo(kb4.w), bfhi(kb4.w));
            *(float4*)&vt[sr][shf + 0]  = make_float4(bflo(va.x), bfhi(va.x), bflo(va.y), bfhi(va.y));
            *(float4*)&vt[sr][shf + 4]  = make_float4(bflo(va.z), bfhi(va.z), bflo(va.w), bfhi(va.w));
            *(float4*)&vt[sr][shf + 8]  = make_float4(bflo(vb4.x), bfhi(vb4.x), bflo(vb4.y), bfhi(vb4.y));
            *(float4*)&vt[sr][shf + 12] = make_float4(bflo(vb4.z), bfhi(vb4.z), bflo(vb4.w), bfhi(vb4.w));
        }
        if (tid < 64) dec_s[tid] = sc * __expf(-tdv * (float)(k0 + tid));
        __syncthreads();

        for (int kk = 0; kk < 64; ++kk) {
            float acc = 0.f;
#pragma unroll
            for (int d4 = 0; d4 < 8; ++d4) {
                float4 kv = *(const float4*)&kt[kk][d4 * 4];
                acc += qreg[d4*4+0] * kv.x + qreg[d4*4+1] * kv.y
                     + qreg[d4*4+2] * kv.z + qreg[d4*4+3] * kv.w;
            }
            float sv = acc * dec_s[kk];
            float e  = __expf(sv);
            float sg = 1.f / (1.f + __expf(-sv));
            float p  = e * sg;
            l += e;
#pragma unroll
            for (int d4 = 0; d4 < 8; ++d4) {
                float4 vv = *(const float4*)&vt[kk][d4 * 4];
                O[d4*4+0] += p * vv.x; O[d4*4+1] += p * vv.y;
                O[d4*4+2] += p * vv.z; O[d4*4+3] += p * vv.w;
            }
        }
    }

    if (kcr < SEQ_) {
        l += (float)(SEQ_ - kcr);                 // exp(0-0) per tail key
#pragma unroll
        for (int d = 0; d < 32; ++d) O[d] += 0.5f * vts_s[d];
    }
    float invL = 1.f / l;

    unsigned short* obf = ctxbf + ((size_t)(b * SEQ_ + qrow)) * D_ + hh * DK_;
#pragma unroll
    for (int wq = 0; wq < 4; ++wq) {
        uint4 u;
        u.x = (unsigned)f2bf(O[wq*8+0]*invL) | ((unsigned)f2bf(O[wq*8+1]*invL) << 16);
        u.y = (unsigned)f2bf(O[wq*8+2]*invL) | ((unsigned)f2bf(O[wq*8+3]*invL) << 16);
        u.z = (unsigned)f2bf(O[wq*8+4]*invL) | ((unsigned)f2bf(O[wq*8+5]*invL) << 16);
        u.w = (unsigned)f2bf(O[wq*8+6]*invL) | ((unsigned)f2bf(O[wq*8+7]*invL) << 16);
        ((uint4*)obf)[wq] = u;
    }
}

// ---------------------------------------------------------------------------
// Kernel 4: o-proj + residual + LN1. 16 rows x 256 cols per block.
// ---------------------------------------------------------------------------
__global__ __launch_bounds__(256) void oproj_ln1(
    const unsigned short* __restrict__ ctx, const unsigned short* __restrict__ wo,
    const float* __restrict__ ob, const float* __restrict__ resid,
    const float* __restrict__ g1, const float* __restrict__ bt1,
    float* __restrict__ h1out, unsigned short* __restrict__ h1bf)
{
    __shared__ unsigned short As[2][512];
    __shared__ unsigned short Bs[2][8192];
    __shared__ float lsum[4][16], lsq[4][16], mean_s[16], inv_s[16];

    int tid = threadIdx.x;
    int wave = tid >> 6, lane = tid & 63;
    int bm = blockIdx.x * 16;
    int fr = lane & 15, kb = lane >> 4;
    int q = kb, cl = fr;
    int swz = (fr >> 1) & 3;

    const unsigned short* gpB[4];
    int dstB[4];
#pragma unroll
    for (int i = 0; i < 4; ++i) {
        int sB = i * 256 + tid;
        int r = sB >> 2, ck = (sB & 3) ^ ((r >> 1) & 3);
        gpB[i] = wo + (size_t)r * 256 + ck * 8;
        dstB[i] = sB * 8;
    }
    const unsigned short* gpA = nullptr;
    if (tid < 64) {
        int r = tid >> 2, ck = (tid & 3) ^ ((r >> 1) & 3);
        gpA = ctx + (size_t)(bm + r) * 256 + ck * 8;
    }

    int oA = fr * 32 + ((kb ^ swz) * 8);
    int oB[4];
#pragma unroll
    for (int t = 0; t < 4; ++t) {
        int n = wave * 64 + t * 16 + fr;
        oB[t] = n * 32 + ((kb ^ swz) * 8);
    }

    f32x4 acc[4];
#pragma unroll
    for (int j = 0; j < 4; ++j) acc[j] = (f32x4){0.f, 0.f, 0.f, 0.f};

    auto stage = [&](int s, int dd) {
#pragma unroll
        for (int i = 0; i < 4; ++i) gload_lds16(gpB[i] + s * 32, &Bs[dd][dstB[i]]);
        if (tid < 64) gload_lds16(gpA + s * 32, &As[dd][tid * 8]);
    };

    stage(0, 0);
    __syncthreads();
    for (int s = 0; s < 8; ++s) {
        int dd = s & 1;
        if (s + 1 < 8) stage(s + 1, dd ^ 1);
        bf16x8 af = *(const bf16x8*)&As[dd][oA];
#pragma unroll
        for (int j = 0; j < 4; ++j)
            acc[j] = __builtin_amdgcn_mfma_f32_16x16x32_bf16(
                af, *(const bf16x8*)&Bs[dd][oB[j]], acc[j], 0, 0, 0);
        __syncthreads();
    }

    float zsum[4] = {0.f, 0.f, 0.f, 0.f}, zsq[4] = {0.f, 0.f, 0.f, 0.f};
    float zv[4][4];
#pragma unroll
    for (int ct = 0; ct < 4; ++ct) {
        int col = wave * 64 + ct * 16 + cl;
        float bj = ob[col];
#pragma unroll
        for (int r = 0; r < 4; ++r) {
            int row = bm + q * 4 + r;
            float z = acc[ct][r] + bj + resid[(size_t)row * 256 + col];
            zv[ct][r] = z;
            zsum[r] += z;
            zsq[r]  += z * z;
        }
    }
#pragma unroll
    for (int r = 0; r < 4; ++r) {
#pragma unroll
        for (int off = 1; off < 16; off <<= 1) {
            zsum[r] += __shfl_xor(zsum[r], off);
            zsq[r]  += __shfl_xor(zsq[r], off);
        }
    }
    if (cl == 0) {
#pragma unroll
        for (int r = 0; r < 4; ++r) {
            lsum[wave][q * 4 + r] = zsum[r];
            lsq[wave][q * 4 + r]  = zsq[r];
        }
    }
    __syncthreads();
    if (tid < 16) {
        float s  = lsum[0][tid] + lsum[1][tid] + lsum[2][tid] + lsum[3][tid];
        float sq = lsq[0][tid] + lsq[1][tid] + lsq[2][tid] + lsq[3][tid];
        float mean = s * (1.f / 256.f);
        float var  = sq * (1.f / 256.f) - mean * mean;
        mean_s[tid] = mean;
        inv_s[tid]  = rsqrtf(var + 1e-5f);
    }
    __syncthreads();

#pragma unroll
    for (int ct = 0; ct < 4; ++ct) {
        int col = wave * 64 + ct * 16 + cl;
        float gc = g1[col], bc = bt1[col];
#pragma unroll
        for (int r = 0; r < 4; ++r) {
            int lr = q * 4 + r;
            float o = (zv[ct][r] - mean_s[lr]) * inv_s[lr] * gc + bc;
            size_t off = (size_t)(bm + lr) * 256 + col;
            h1out[off] = o;
            h1bf[off]  = f2bf(o);
        }
    }
}

// ---------------------------------------------------------------------------
// Kernel 5: fused FFN chunk, double-buffered staging in both phases.
// ---------------------------------------------------------------------------
__global__ __launch_bounds__(256) void ffn_fused(
    const unsigned short* __restrict__ h1bf, const unsigned short* __restrict__ w1,
    const float* __restrict__ f1b, const unsigned short* __restrict__ w2,
    float* __restrict__ part)
{
    __shared__ unsigned short As[2][1024];
    __shared__ unsigned short Bs[2][8192];
    __shared__ unsigned short ffs[32 * 264];

    int tid = threadIdx.x;
    int wave = tid >> 6, lane = tid & 63;
    int c = blockIdx.x;
    int bm = blockIdx.y * 32;
    int fr = lane & 15, kb = lane >> 4;
    int q = kb, cl = fr;

    const unsigned short* gB1[4];
    const unsigned short* gB2[4];
    int dstB[4];
#pragma unroll
    for (int i = 0; i < 4; ++i) {
        int sB = i * 256 + tid;
        int r = sB >> 2, ck = (sB & 3) ^ ((r >> 1) & 3);
        gB1[i] = w1 + (size_t)(c * 256 + r) * 256 + ck * 8;
        gB2[i] = w2 + (size_t)r * 1024 + c * 256 + ck * 8;
        dstB[i] = sB * 8;
    }
    const unsigned short* gA = nullptr;
    if (tid < 128) {
        int ar = tid >> 2, ack = (tid & 3) ^ ((ar >> 1) & 3);
        gA = h1bf + (size_t)(bm + ar) * 256 + ack * 8;
    }

    int oA1[2], oB[4];
#pragma unroll
    for (int t = 0; t < 2; ++t) {
        int m = t * 16 + fr;
        oA1[t] = m * 32 + ((kb ^ ((m >> 1) & 3)) * 8);
    }
#pragma unroll
    for (int t = 0; t < 4; ++t) {
        int n = wave * 64 + t * 16 + fr;
        oB[t] = n * 32 + ((kb ^ ((n >> 1) & 3)) * 8);
    }

    auto stage1 = [&](int s, int dd) {
#pragma unroll
        for (int i = 0; i < 4; ++i) gload_lds16(gB1[i] + s * 32, &Bs[dd][dstB[i]]);
        if (tid < 128) gload_lds16(gA + s * 32, &As[dd][tid * 8]);
    };
    auto stage2 = [&](int s, int dd) {
#pragma unroll
        for (int i = 0; i < 4; ++i) gload_lds16(gB2[i] + s * 32, &Bs[dd][dstB[i]]);
    };

    f32x4 a1[2][4];
#pragma unroll
    for (int i = 0; i < 2; ++i)
#pragma unroll
        for (int j = 0; j < 4; ++j) a1[i][j] = (f32x4){0.f, 0.f, 0.f, 0.f};

    stage1(0, 0);
    __syncthreads();
    for (int ks = 0; ks < 8; ++ks) {
        int dd = ks & 1;
        if (ks + 1 < 8) stage1(ks + 1, dd ^ 1);
        bf16x8 af[2], bfv[4];
#pragma unroll
        for (int t = 0; t < 2; ++t) af[t] = *(const bf16x8*)&As[dd][oA1[t]];
#pragma unroll
        for (int t = 0; t < 4; ++t) bfv[t] = *(const bf16x8*)&Bs[dd][oB[t]];
#pragma unroll
        for (int i = 0; i < 2; ++i)
#pragma unroll
            for (int j = 0; j < 4; ++j)
                a1[i][j] = __builtin_amdgcn_mfma_f32_16x16x32_bf16(af[i], bfv[j], a1[i][j], 0, 0, 0);
        __syncthreads();
    }

#pragma unroll
    for (int ct = 0; ct < 4; ++ct) {
        int col = wave * 64 + ct * 16 + cl;
        float bj = f1b[c * 256 + col];
#pragma unroll
        for (int rt = 0; rt < 2; ++rt)
#pragma unroll
            for (int r = 0; r < 4; ++r) {
                float v = fmaxf(a1[rt][ct][r] + bj, 0.f);
                ffs[(rt * 16 + q * 4 + r) * 264 + col] = f2bf(v);
            }
    }

    f32x4 a2[2][4];
#pragma unroll
    for (int i = 0; i < 2; ++i)
#pragma unroll
        for (int j = 0; j < 4; ++j) a2[i][j] = (f32x4){0.f, 0.f, 0.f, 0.f};

    stage2(0, 0);
    __syncthreads();
    for (int ks = 0; ks < 8; ++ks) {
        int dd = ks & 1;
        if (ks + 1 < 8) stage2(ks + 1, dd ^ 1);
        bf16x8 af[2], bfv[4];
#pragma unroll
        for (int t = 0; t < 2; ++t)
            af[t] = *(const bf16x8*)&ffs[(t * 16 + fr) * 264 + ks * 32 + kb * 8];
#pragma unroll
        for (int t = 0; t < 4; ++t) bfv[t] = *(const bf16x8*)&Bs[dd][oB[t]];
#pragma unroll
        for (int i = 0; i < 2; ++i)
#pragma unroll
            for (int j = 0; j < 4; ++j)
                a2[i][j] = __builtin_amdgcn_mfma_f32_16x16x32_bf16(af[i], bfv[j], a2[i][j], 0, 0, 0);
        __syncthreads();
    }

#pragma unroll
    for (int ct = 0; ct < 4; ++ct) {
        int col = wave * 64 + ct * 16 + cl;
#pragma unroll
        for (int rt = 0; rt < 2; ++rt)
#pragma unroll
            for (int r = 0; r < 4; ++r)
                part[((size_t)c * 4096 + bm + rt * 16 + q * 4 + r) * 256 + col] = a2[rt][ct][r];
    }
}

// ---------------------------------------------------------------------------
// Kernel 6: merge FFN2 partials + bias + h1 residual + LN2 (+final fold).
// ---------------------------------------------------------------------------
__global__ __launch_bounds__(256) void merge_ln2(
    const float* __restrict__ h1, const float* __restrict__ part,
    const float* __restrict__ f2b, const float* __restrict__ g2,
    const float* __restrict__ bt2,
    float* __restrict__ hout, unsigned short* __restrict__ hbf,
    const float* __restrict__ outW, const float* __restrict__ outb,
    float* __restrict__ out, int doFinal,
    float* __restrict__ hts1, int doHts)
{
    __shared__ float red[4][256];

    int wrp = threadIdx.x >> 6;
    int row = blockIdx.x * 4 + wrp;
    int lane = threadIdx.x & 63;
    int d = lane * 4;

    float4 z = *(const float4*)(h1 + (size_t)row * 256 + d);
    float4 b4 = *(const float4*)(f2b + d);
    z.x += b4.x; z.y += b4.y; z.z += b4.z; z.w += b4.w;
#pragma unroll
    for (int c = 0; c < 4; ++c) {
        float4 p = *(const float4*)(part + ((size_t)c * 4096 + row) * 256 + d);
        z.x += p.x; z.y += p.y; z.z += p.z; z.w += p.w;
    }

    float s = z.x + z.y + z.z + z.w;
    float ss = z.x * z.x + z.y * z.y + z.z * z.z + z.w * z.w;
#pragma unroll
    for (int off = 1; off < 64; off <<= 1) {
        s += __shfl_xor(s, off);
        ss += __shfl_xor(ss, off);
    }
    float mean = s * (1.f / 256.f);
    float var = ss * (1.f / 256.f) - mean * mean;
    float inv = rsqrtf(var + 1e-5f);

    float4 g4 = *(const float4*)(g2 + d);
    float4 t4 = *(const float4*)(bt2 + d);
    float4 o;
    o.x = (z.x - mean) * inv * g4.x + t4.x;
    o.y = (z.y - mean) * inv * g4.y + t4.y;
    o.z = (z.z - mean) * inv * g4.z + t4.z;
    o.w = (z.w - mean) * inv * g4.w + t4.w;
    *(float4*)(hout + (size_t)row * 256 + d) = o;
    unsigned short s0 = f2bf(o.x), s1 = f2bf(o.y), s2 = f2bf(o.z), s3 = f2bf(o.w);
    unsigned int u01 = (unsigned)s0 | ((unsigned)s1 << 16);
    unsigned int u23 = (unsigned)s2 | ((unsigned)s3 << 16);
    *(uint2*)&hbf[(size_t)row * 256 + d] = make_uint2(u01, u23);

    if (doHts) {
        *(float4*)&red[wrp][d] = make_float4(bf2f(s0), bf2f(s1), bf2f(s2), bf2f(s3));
        __syncthreads();
        int cidx = threadIdx.x;
        float cs = red[0][cidx] + red[1][cidx] + red[2][cidx] + red[3][cidx];
        int b = blockIdx.x >> 9;
        int tile = (blockIdx.x >> 3) & 63;
        atomicAdd(&hts1[((b << 6) + tile) * 256 + cidx], cs);
    }

    if (doFinal && (row == 2047 || row == 4095)) {
        float4 w4 = *(const float4*)(outW + d);
        float s2f = o.x * w4.x + o.y * w4.y + o.z * w4.z + o.w * w4.w;
#pragma unroll
        for (int off = 1; off < 64; off <<= 1) s2f += __shfl_xor(s2f, off);
        if (lane == 0) out[row >> 11] = s2f * 0.5f + outb[0];
    }
}

// ---------------------------------------------------------------------------
extern "C" void kernel_launch(void* const* d_in, const int* in_sizes, int n_in,
                              void* d_out, int out_size, void* d_ws, size_t ws_size,
                              hipStream_t stream)
{
    (void)in_sizes; (void)n_in; (void)out_size; (void)ws_size;
    const float* x      = (const float*)d_in[0];
    const float* conv_w = (const float*)d_in[1];
    const float* conv_b = (const float*)d_in[2];
    const float* bn_g   = (const float*)d_in[3];
    const float* bn_b   = (const float*)d_in[4];
    const float* pe     = (const float*)d_in[5];
    const float* qW     = (const float*)d_in[6];
    const float* qb     = (const float*)d_in[7];
    const float* kW     = (const float*)d_in[8];
    const float* kb     = (const float*)d_in[9];
    const float* vW     = (const float*)d_in[10];
    const float* vb     = (const float*)d_in[11];
    const float* oW     = (const float*)d_in[12];
    const float* ob     = (const float*)d_in[13];
    const float* scale  = (const float*)d_in[14];
    const float* td     = (const float*)d_in[15];
    const float* ln1g   = (const float*)d_in[16];
    const float* ln1b   = (const float*)d_in[17];
    const float* f1W    = (const float*)d_in[18];
    const float* f1b    = (const float*)d_in[19];
    const float* f2W    = (const float*)d_in[20];
    const float* f2b    = (const float*)d_in[21];
    const float* ln2g   = (const float*)d_in[22];
    const float* ln2b   = (const float*)d_in[23];
    const float* outW   = (const float*)d_in[24];
    const float* outb   = (const float*)d_in[25];
    float* out = (float*)d_out;

    float* ws = (float*)d_ws;
    const size_t MT = (size_t)B_ * SEQ_ * D_;      // 1,048,576
    const size_t HTS = (size_t)B_ * 64 * 256;      // 32,768
    float* h     = ws;                             // MT fp32
    float* h1    = ws + MT;                        // MT fp32
    float* part  = ws + 2 * MT;                    // 4*MT fp32
    float* hts0  = ws + 6 * MT;                    // 32768 fp32
    float* hts1  = hts0 + HTS;                     // 32768 fp32
    float* vts_g = hts1 + HTS;                     // 512 fp32
    unsigned short* bfb = (unsigned short*)(vts_g + 512);
    unsigned short* h_bf   = bfb;
    unsigned short* ctx_bf = bfb + MT;
    unsigned short* q_bf   = bfb + 2 * MT;
    unsigned short* k_bf   = bfb + 3 * MT;
    unsigned short* v_bf   = bfb + 4 * MT;
    unsigned short* h1_bf  = bfb + 5 * MT;
    unsigned short* wq_bf  = bfb + 6 * MT;
    unsigned short* wk_bf  = wq_bf + MT / 8;
    unsigned short* wv_bf  = wk_bf + MT / 8;
    unsigned short* wo_bf  = wv_bf + MT / 8;
    unsigned short* wf1_bf = wo_bf + MT / 8;
    unsigned short* wf2_bf = wf1_bf + MT / 2;

    const int Mrows = B_ * SEQ_;                   // 4096

    prep_kernel<<<768 + 128, 256, 0, stream>>>(
        x, conv_w, conv_b, bn_g, bn_b, pe, h, h_bf,
        qW, kW, vW, oW, f1W, f2W,
        wq_bf, wk_bf, wv_bf, wo_bf, wf1_bf, wf2_bf, hts0, hts1);

    for (int l = 0; l < L_; ++l) {
        const unsigned short* wq_l  = wq_bf  + (size_t)l * D_ * D_;
        const unsigned short* wk_l  = wk_bf  + (size_t)l * D_ * D_;
        const unsigned short* wv_l  = wv_bf  + (size_t)l * D_ * D_;
        const unsigned short* wo_l  = wo_bf  + (size_t)l * D_ * D_;
        const unsigned short* wf1_l = wf1_bf + (size_t)l * DFF_ * D_;
        const unsigned short* wf2_l = wf2_bf + (size_t)l * DFF_ * D_;
        const float* hts_l = (l == 0) ? hts0 : hts1;

        gemm_qkv<<<dim3(D_ / 64, Mrows / 64, 4), 256, 0, stream>>>(
            h_bf, wq_l, wk_l, wv_l, qb + l * D_, kb + l * D_, vb + l * D_,
            q_bf, k_bf, v_bf, td + l * H_, hts_l, vts_g, Mrows, D_, D_);

        attn_kernel<<<dim3(SEQ_ / 128, H_, B_), 128, 0, stream>>>(
            q_bf, k_bf, v_bf, vts_g, ctx_bf, scale + l, td + l * H_);

        oproj_ln1<<<Mrows / 16, 256, 0, stream>>>(
            ctx_bf, wo_l, ob + l * D_, h,
            ln1g + l * D_, ln1b + l * D_, h1, h1_bf);

        ffn_fused<<<dim3(4, Mrows / 32), 256, 0, stream>>>(
            h1_bf, wf1_l, f1b + l * DFF_, wf2_l, part);

        merge_ln2<<<Mrows / 4, 256, 0, stream>>>(
            h1, part, f2b + l * D_, ln2g + l * D_, ln2b + l * D_,
            h, h_bf, outW, outb, out, (l == L_ - 1) ? 1 : 0,
            hts1, (l == 0) ? 1 : 0);
    }
}

// Round 6
// 207.718 us; speedup vs baseline: 1.1511x; 1.1511x over previous
//
#include <hip/hip_runtime.h>
#include <math.h>

#define B_    2
#define SEQ_  2048
#define D_    256
#define H_    8
#define DK_   32
#define L_    2
#define DFF_  1024

#define TD_CUT 44.0f

typedef short  bf16x8 __attribute__((ext_vector_type(8)));
typedef float  f32x4  __attribute__((ext_vector_type(4)));

__device__ __forceinline__ int compute_kcut(float tdv) {
    int kcut = SEQ_;
    if (tdv > 1e-9f) {
        float kc = TD_CUT / tdv;
        kcut = (kc >= (float)SEQ_) ? SEQ_ : ((int)kc + 1);
    }
    int kcr = (kcut + 63) & ~63;          // 64-granular: whole K-tiles
    if (kcr > SEQ_) kcr = SEQ_;
    return kcr;
}

__device__ __forceinline__ unsigned short f2bf(float f) {
    unsigned int u = __float_as_uint(f);
    unsigned int r = u + 0x7FFFu + ((u >> 16) & 1u);   // RNE
    return (unsigned short)(r >> 16);
}
__device__ __forceinline__ float bf2f(unsigned short u) {
    return __uint_as_float(((unsigned int)u) << 16);
}
__device__ __forceinline__ float bflo(unsigned int u) {
    return __uint_as_float(u << 16);
}
__device__ __forceinline__ float bfhi(unsigned int u) {
    return __uint_as_float(u & 0xFFFF0000u);
}

__device__ __forceinline__ void gload_lds16(const unsigned short* g, unsigned short* l) {
    __builtin_amdgcn_global_load_lds(
        (const __attribute__((address_space(1))) unsigned int*)(const unsigned int*)g,
        (__attribute__((address_space(3))) unsigned int*)(unsigned int*)l,
        16, 0, 0);
}

// ---------------------------------------------------------------------------
// Kernel 1: prep = weight cvt (blocks 0..767) + conv/pe/hts0 (blocks 768..895).
// ---------------------------------------------------------------------------
__global__ __launch_bounds__(256) void prep_kernel(
    const float* __restrict__ x, const float* __restrict__ w,
    const float* __restrict__ cb, const float* __restrict__ bg,
    const float* __restrict__ bb, const float* __restrict__ pe,
    float* __restrict__ h, unsigned short* __restrict__ hbf,
    const float* __restrict__ p0, const float* __restrict__ p1,
    const float* __restrict__ p2, const float* __restrict__ p3,
    const float* __restrict__ p4, const float* __restrict__ p5,
    unsigned short* __restrict__ q0, unsigned short* __restrict__ q1,
    unsigned short* __restrict__ q2, unsigned short* __restrict__ q3,
    unsigned short* __restrict__ q4, unsigned short* __restrict__ q5,
    float* __restrict__ hts0, float* __restrict__ hts1)
{
    int bid = blockIdx.x;
    if (bid < 768) {                              // ---- cvt path
        int t = bid * 256 + threadIdx.x;
        const float* src; unsigned short* dst; int base;
        if (t < 65536) {
            int a = t >> 14;
            src = a == 0 ? p0 : a == 1 ? p1 : a == 2 ? p2 : p3;
            dst = a == 0 ? q0 : a == 1 ? q1 : a == 2 ? q2 : q3;
            base = (t & 16383) * 8;
        } else {
            int u = t - 65536;
            int a = u >> 16;
            src = a ? p5 : p4;
            dst = a ? q5 : q4;
            base = (u & 65535) * 8;
        }
        float4 v0 = *(const float4*)(src + base);
        float4 v1 = *(const float4*)(src + base + 4);
        bf16x8 o;
        o[0] = (short)f2bf(v0.x); o[1] = (short)f2bf(v0.y);
        o[2] = (short)f2bf(v0.z); o[3] = (short)f2bf(v0.w);
        o[4] = (short)f2bf(v1.x); o[5] = (short)f2bf(v1.y);
        o[6] = (short)f2bf(v1.z); o[7] = (short)f2bf(v1.w);
        *(bf16x8*)(dst + base) = o;
        return;
    }
    // ---- conv path: block = (b, tile of 32 rows); thread = column d
    int bid2 = bid - 768;                         // 0..127
    int b    = bid2 >> 6;
    int tile = bid2 & 63;
    int d    = threadIdx.x;

    hts1[bid2 * 256 + d] = 0.f;

    const float* xp = x + b * SEQ_;
    float w0 = w[d * 3 + 0], w1v = w[d * 3 + 1], w2v = w[d * 3 + 2];
    float gg  = rsqrtf(1.f + 1e-5f) * bg[d];
    float cbd = cb[d], bbd = bb[d];

    int s0 = tile * 32;
    float xm1 = (s0 > 0) ? xp[s0 - 1] : 0.f;
    float x0v = xp[s0];
    float hsum = 0.f;
#pragma unroll 4
    for (int r = 0; r < 32; ++r) {
        int s = s0 + r;
        float xp1 = (s < SEQ_ - 1) ? xp[s + 1] : 0.f;
        float acc = xm1 * w0 + x0v * w1v + xp1 * w2v + cbd;
        acc = acc * gg + bbd;
        acc = fmaxf(acc, 0.f);
        float v = acc + pe[s * D_ + d];
        size_t idx = ((size_t)(b * SEQ_ + s)) * D_ + d;
        h[idx] = v;
        unsigned short ub = f2bf(v);
        hbf[idx] = ub;
        hsum += bf2f(ub);
        xm1 = x0v; x0v = xp1;
    }
    hts0[(b * 64 + tile) * 256 + d] = hsum;
}

// ---------------------------------------------------------------------------
// Kernel 2: q/k/v GEMM (bf16 in/out), BK=64 double-buffered pipeline.
// z==3 slice: vtail precompute — vts_g[b][h][32] from hts suffix-sum . Wv.
// K/V blocks (z==1,2) with rows >= kcut exit immediately.
// ---------------------------------------------------------------------------
__global__ __launch_bounds__(256) void gemm_qkv(
    const unsigned short* __restrict__ A,
    const unsigned short* __restrict__ W0, const unsigned short* __restrict__ W1,
    const unsigned short* __restrict__ W2,
    const float* __restrict__ b0, const float* __restrict__ b1,
    const float* __restrict__ b2,
    unsigned short* __restrict__ O0, unsigned short* __restrict__ O1,
    unsigned short* __restrict__ O2,
    const float* __restrict__ td_l,
    const float* __restrict__ hts_l, float* __restrict__ vts_g,
    int M, int N, int K)
{
    __shared__ unsigned short As[2][2][2048];     // [buf][k-slab][64x32]
    __shared__ unsigned short Bs[2][2][2048];
    __shared__ float hsc[256];

    int z = blockIdx.z;
    int tid  = threadIdx.x;

    if (z == 3) {                                 // ---- vtail path
        if (blockIdx.x != 0 || blockIdx.y >= 16) return;
        int hh = blockIdx.y & 7;
        int b  = blockIdx.y >> 3;
        int kcr = compute_kcut(td_l[hh]);
        if (kcr >= SEQ_) return;                  // no tail needed
        int tcut = kcr >> 5;                      // 32-row tile units (even)
        // Phase A: masked suffix column-sum over 64 tiles (fully unrolled)
        const float* hb = hts_l + (size_t)b * 64 * 256 + tid;
        float s = 0.f;
#pragma unroll
        for (int t = 0; t < 64; ++t) {
            float v = hb[t * 256];
            s += (t >= tcut) ? v : 0.f;
        }
        hsc[tid] = s;
        __syncthreads();
        // Phase B: vts[j] = hsc . Wv[hh*32+j] + (SEQ-kcr)*vb
        int j = tid >> 3, e = tid & 7;
        const unsigned short* wrow = W2 + (size_t)(hh * 32 + j) * 256 + e * 32;
        float dot = 0.f;
#pragma unroll
        for (int i = 0; i < 4; ++i) {
            bf16x8 w8 = *(const bf16x8*)(wrow + i * 8);
#pragma unroll
            for (int t2 = 0; t2 < 8; ++t2)
                dot += hsc[e * 32 + i * 8 + t2] * bf2f((unsigned short)w8[t2]);
        }
        dot += __shfl_xor(dot, 1);
        dot += __shfl_xor(dot, 2);
        dot += __shfl_xor(dot, 4);
        if (e == 0)
            vts_g[(b * H_ + hh) * 32 + j] = dot + (float)(SEQ_ - kcr) * b2[hh * 32 + j];
        return;
    }

    int bm = blockIdx.y * 64, bn = blockIdx.x * 64;
    if (z > 0) {
        float tdmin = td_l[0];
#pragma unroll
        for (int i = 1; i < H_; ++i) tdmin = fminf(tdmin, td_l[i]);
        if ((bm & (SEQ_ - 1)) >= compute_kcut(tdmin)) return;   // block-uniform
    }
    const unsigned short* W = (z == 0) ? W0 : (z == 1) ? W1 : W2;
    const float* bias = (z == 0) ? b0 : (z == 1) ? b1 : b2;
    unsigned short* C = (z == 0) ? O0 : (z == 1) ? O1 : O2;

    int wave = tid >> 6, lane = tid & 63;
    int wm = (wave & 1) * 32, wn = (wave >> 1) * 32;

    int sr  = tid >> 2;
    int scb = (tid & 3) ^ ((sr >> 1) & 3);
    const unsigned short* aG = A + (size_t)(bm + sr) * K + scb * 8;
    const unsigned short* wG = W + (size_t)(bn + sr) * K + scb * 8;

    int fr = lane & 15;
    int kb = lane >> 4;
    int cbo = (kb ^ ((fr >> 1) & 3)) * 8;
    int oA0 = (wm + fr) * 32 + cbo;
    int oA1 = (wm + 16 + fr) * 32 + cbo;
    int oB0 = (wn + fr) * 32 + cbo;
    int oB1 = (wn + 16 + fr) * 32 + cbo;

    f32x4 acc[2][2];
#pragma unroll
    for (int i = 0; i < 2; ++i)
#pragma unroll
        for (int j = 0; j < 2; ++j) acc[i][j] = (f32x4){0.f, 0.f, 0.f, 0.f};

    auto stage = [&](int s, int dd) {
        gload_lds16(aG + s * 64,      &As[dd][0][tid * 8]);
        gload_lds16(aG + s * 64 + 32, &As[dd][1][tid * 8]);
        gload_lds16(wG + s * 64,      &Bs[dd][0][tid * 8]);
        gload_lds16(wG + s * 64 + 32, &Bs[dd][1][tid * 8]);
    };

    int nst = K >> 6;                              // 4 steps (BK=64)
    stage(0, 0);
    __syncthreads();
    for (int s = 0; s < nst; ++s) {
        int dd = s & 1;
        if (s + 1 < nst) stage(s + 1, dd ^ 1);
#pragma unroll
        for (int kk = 0; kk < 2; ++kk) {
            bf16x8 a0f = *(const bf16x8*)&As[dd][kk][oA0];
            bf16x8 a1f = *(const bf16x8*)&As[dd][kk][oA1];
            bf16x8 b0f = *(const bf16x8*)&Bs[dd][kk][oB0];
            bf16x8 b1f = *(const bf16x8*)&Bs[dd][kk][oB1];
            acc[0][0] = __builtin_amdgcn_mfma_f32_16x16x32_bf16(a0f, b0f, acc[0][0], 0, 0, 0);
            acc[0][1] = __builtin_amdgcn_mfma_f32_16x16x32_bf16(a0f, b1f, acc[0][1], 0, 0, 0);
            acc[1][0] = __builtin_amdgcn_mfma_f32_16x16x32_bf16(a1f, b0f, acc[1][0], 0, 0, 0);
            acc[1][1] = __builtin_amdgcn_mfma_f32_16x16x32_bf16(a1f, b1f, acc[1][1], 0, 0, 0);
        }
        __syncthreads();
    }

    int crow = (lane >> 4) * 4;
    int ccol = lane & 15;
#pragma unroll
    for (int j = 0; j < 2; ++j) {
        float bj = bias[bn + wn + j * 16 + ccol];
#pragma unroll
        for (int i = 0; i < 2; ++i) {
#pragma unroll
            for (int r = 0; r < 4; ++r) {
                float v = acc[i][j][r] + bj;
                C[(size_t)(bm + wm + i * 16 + crow + r) * N + bn + wn + j * 16 + ccol] = f2bf(v);
            }
        }
    }
}

// ---------------------------------------------------------------------------
// Kernel 3: decay-truncated attention. 128 threads = 32 q-rows x 4-way key
// split; grid (SEQ/32, H, B) = 1024 blocks -> 8 waves/CU (TLP hides LDS
// latency; each thread's serial chain is only 8 keys/tile). Softmax shift
// fixed at 0 (tail guarantees the reference; scores O(1)) => the 4-way
// merge is purely additive: shfl-sum l and O, no max/rescale, no LDS merge.
// Tail: l += SEQ-kcr, O += 0.5*vts (vts precomputed by gemm z==3).
// ---------------------------------------------------------------------------
__global__ __launch_bounds__(128) void attn_kernel(
    const unsigned short* __restrict__ q, const unsigned short* __restrict__ k,
    const unsigned short* __restrict__ v, const float* __restrict__ vts_g,
    unsigned short* __restrict__ ctxbf,
    const float* __restrict__ scale_p, const float* __restrict__ td_l)
{
    int b = blockIdx.z, hh = blockIdx.y;
    int tid = threadIdx.x;
    int row = tid >> 2;
    int sp  = tid & 3;
    int qrow = blockIdx.x * 32 + row;

    float sc  = 0.17677669529663687f * scale_p[0];
    float tdv = td_l[hh];
    int kcr = compute_kcut(tdv);                  // block-uniform, 64-granular
    int ntiles = kcr >> 5;                        // 32-key tiles

    __shared__ float kt[32][36];
    __shared__ float vt[32][36];
    __shared__ float vts_s[32];

    if (tid < 32) vts_s[tid] = vts_g[(b * H_ + hh) * 32 + tid];

    const unsigned short* qptr = q + ((size_t)(b * SEQ_ + qrow)) * D_ + hh * DK_;
    float qreg[32];
#pragma unroll
    for (int j = 0; j < 4; ++j) {
        uint4 u = ((const uint4*)qptr)[j];
        qreg[j*8+0] = bflo(u.x); qreg[j*8+1] = bfhi(u.x);
        qreg[j*8+2] = bflo(u.y); qreg[j*8+3] = bfhi(u.y);
        qreg[j*8+4] = bflo(u.z); qreg[j*8+5] = bfhi(u.z);
        qreg[j*8+6] = bflo(u.w); qreg[j*8+7] = bfhi(u.w);
    }

    float O[32];
#pragma unroll
    for (int d = 0; d < 32; ++d) O[d] = 0.f;
    float l = 0.f;

    for (int t = 0; t < ntiles; ++t) {
        int k0 = t * 32;
        if (t > 0) __syncthreads();               // WAR on kt/vt
        {
            int r = tid >> 2, c8 = (tid & 3) * 8;
            size_t goff = ((size_t)(b * SEQ_ + k0 + r)) * D_ + hh * DK_ + c8;
            uint4 uk = *(const uint4*)(k + goff);
            uint4 uv = *(const uint4*)(v + goff);
            *(float4*)&kt[r][c8]     = make_float4(bflo(uk.x), bfhi(uk.x), bflo(uk.y), bfhi(uk.y));
            *(float4*)&kt[r][c8 + 4] = make_float4(bflo(uk.z), bfhi(uk.z), bflo(uk.w), bfhi(uk.w));
            *(float4*)&vt[r][c8]     = make_float4(bflo(uv.x), bfhi(uv.x), bflo(uv.y), bfhi(uv.y));
            *(float4*)&vt[r][c8 + 4] = make_float4(bflo(uv.z), bfhi(uv.z), bflo(uv.w), bfhi(uv.w));
        }
        __syncthreads();

#pragma unroll
        for (int kk = 0; kk < 8; ++kk) {
            int kl = sp * 8 + kk;
            float acc = 0.f;
#pragma unroll
            for (int d4 = 0; d4 < 8; ++d4) {
                float4 kv = *(const float4*)&kt[kl][d4 * 4];
                acc += qreg[d4*4+0] * kv.x + qreg[d4*4+1] * kv.y
                     + qreg[d4*4+2] * kv.z + qreg[d4*4+3] * kv.w;
            }
            float sv = acc * sc * __expf(-tdv * (float)(k0 + kl));
            float e  = __expf(sv);
            float sg = 1.f / (1.f + __expf(-sv));
            float p  = e * sg;
            l += e;
#pragma unroll
            for (int d4 = 0; d4 < 8; ++d4) {
                float4 vv = *(const float4*)&vt[kl][d4 * 4];
                O[d4*4+0] += p * vv.x; O[d4*4+1] += p * vv.y;
                O[d4*4+2] += p * vv.z; O[d4*4+3] += p * vv.w;
            }
        }
    }

    // additive 4-way merge across sp (lanes row*4 + {0,1,2,3})
    l += __shfl_xor(l, 1);
    l += __shfl_xor(l, 2);
#pragma unroll
    for (int d = 0; d < 32; ++d) {
        O[d] += __shfl_xor(O[d], 1);
        O[d] += __shfl_xor(O[d], 2);
    }

    if (kcr < SEQ_) {
        l += (float)(SEQ_ - kcr);                 // exp(0-0) per tail key
#pragma unroll
        for (int d = 0; d < 32; ++d) O[d] += 0.5f * vts_s[d];
    }
    float invL = 1.f / l;

    // each sp lane writes its 8-dim quarter (coalesced 16B per lane)
    int g = sp;
    unsigned int packed[4];
#pragma unroll
    for (int dd = 0; dd < 8; dd += 2) {
        int d0 = g * 8 + dd, d1 = d0 + 1;
        packed[dd >> 1] = (unsigned)f2bf(O[d0] * invL)
                        | ((unsigned)f2bf(O[d1] * invL) << 16);
    }
    unsigned short* obf = ctxbf + ((size_t)(b * SEQ_ + qrow)) * D_ + hh * DK_ + g * 8;
    *(uint4*)obf = make_uint4(packed[0], packed[1], packed[2], packed[3]);
}

// ---------------------------------------------------------------------------
// Kernel 4: o-proj + residual + LN1. 16 rows x 256 cols per block.
// ---------------------------------------------------------------------------
__global__ __launch_bounds__(256) void oproj_ln1(
    const unsigned short* __restrict__ ctx, const unsigned short* __restrict__ wo,
    const float* __restrict__ ob, const float* __restrict__ resid,
    const float* __restrict__ g1, const float* __restrict__ bt1,
    float* __restrict__ h1out, unsigned short* __restrict__ h1bf)
{
    __shared__ unsigned short As[2][512];
    __shared__ unsigned short Bs[2][8192];
    __shared__ float lsum[4][16], lsq[4][16], mean_s[16], inv_s[16];

    int tid = threadIdx.x;
    int wave = tid >> 6, lane = tid & 63;
    int bm = blockIdx.x * 16;
    int fr = lane & 15, kb = lane >> 4;
    int q = kb, cl = fr;
    int swz = (fr >> 1) & 3;

    const unsigned short* gpB[4];
    int dstB[4];
#pragma unroll
    for (int i = 0; i < 4; ++i) {
        int sB = i * 256 + tid;
        int r = sB >> 2, ck = (sB & 3) ^ ((r >> 1) & 3);
        gpB[i] = wo + (size_t)r * 256 + ck * 8;
        dstB[i] = sB * 8;
    }
    const unsigned short* gpA = nullptr;
    if (tid < 64) {
        int r = tid >> 2, ck = (tid & 3) ^ ((r >> 1) & 3);
        gpA = ctx + (size_t)(bm + r) * 256 + ck * 8;
    }

    int oA = fr * 32 + ((kb ^ swz) * 8);
    int oB[4];
#pragma unroll
    for (int t = 0; t < 4; ++t) {
        int n = wave * 64 + t * 16 + fr;
        oB[t] = n * 32 + ((kb ^ swz) * 8);
    }

    f32x4 acc[4];
#pragma unroll
    for (int j = 0; j < 4; ++j) acc[j] = (f32x4){0.f, 0.f, 0.f, 0.f};

    auto stage = [&](int s, int dd) {
#pragma unroll
        for (int i = 0; i < 4; ++i) gload_lds16(gpB[i] + s * 32, &Bs[dd][dstB[i]]);
        if (tid < 64) gload_lds16(gpA + s * 32, &As[dd][tid * 8]);
    };

    stage(0, 0);
    __syncthreads();
    for (int s = 0; s < 8; ++s) {
        int dd = s & 1;
        if (s + 1 < 8) stage(s + 1, dd ^ 1);
        bf16x8 af = *(const bf16x8*)&As[dd][oA];
#pragma unroll
        for (int j = 0; j < 4; ++j)
            acc[j] = __builtin_amdgcn_mfma_f32_16x16x32_bf16(
                af, *(const bf16x8*)&Bs[dd][oB[j]], acc[j], 0, 0, 0);
        __syncthreads();
    }

    float zsum[4] = {0.f, 0.f, 0.f, 0.f}, zsq[4] = {0.f, 0.f, 0.f, 0.f};
    float zv[4][4];
#pragma unroll
    for (int ct = 0; ct < 4; ++ct) {
        int col = wave * 64 + ct * 16 + cl;
        float bj = ob[col];
#pragma unroll
        for (int r = 0; r < 4; ++r) {
            int row = bm + q * 4 + r;
            float z = acc[ct][r] + bj + resid[(size_t)row * 256 + col];
            zv[ct][r] = z;
            zsum[r] += z;
            zsq[r]  += z * z;
        }
    }
#pragma unroll
    for (int r = 0; r < 4; ++r) {
#pragma unroll
        for (int off = 1; off < 16; off <<= 1) {
            zsum[r] += __shfl_xor(zsum[r], off);
            zsq[r]  += __shfl_xor(zsq[r], off);
        }
    }
    if (cl == 0) {
#pragma unroll
        for (int r = 0; r < 4; ++r) {
            lsum[wave][q * 4 + r] = zsum[r];
            lsq[wave][q * 4 + r]  = zsq[r];
        }
    }
    __syncthreads();
    if (tid < 16) {
        float s  = lsum[0][tid] + lsum[1][tid] + lsum[2][tid] + lsum[3][tid];
        float sq = lsq[0][tid] + lsq[1][tid] + lsq[2][tid] + lsq[3][tid];
        float mean = s * (1.f / 256.f);
        float var  = sq * (1.f / 256.f) - mean * mean;
        mean_s[tid] = mean;
        inv_s[tid]  = rsqrtf(var + 1e-5f);
    }
    __syncthreads();

#pragma unroll
    for (int ct = 0; ct < 4; ++ct) {
        int col = wave * 64 + ct * 16 + cl;
        float gc = g1[col], bc = bt1[col];
#pragma unroll
        for (int r = 0; r < 4; ++r) {
            int lr = q * 4 + r;
            float o = (zv[ct][r] - mean_s[lr]) * inv_s[lr] * gc + bc;
            size_t off = (size_t)(bm + lr) * 256 + col;
            h1out[off] = o;
            h1bf[off]  = f2bf(o);
        }
    }
}

// ---------------------------------------------------------------------------
// Kernel 5: fused FFN chunk, double-buffered staging in both phases.
// ---------------------------------------------------------------------------
__global__ __launch_bounds__(256) void ffn_fused(
    const unsigned short* __restrict__ h1bf, const unsigned short* __restrict__ w1,
    const float* __restrict__ f1b, const unsigned short* __restrict__ w2,
    float* __restrict__ part)
{
    __shared__ unsigned short As[2][1024];
    __shared__ unsigned short Bs[2][8192];
    __shared__ unsigned short ffs[32 * 264];

    int tid = threadIdx.x;
    int wave = tid >> 6, lane = tid & 63;
    int c = blockIdx.x;
    int bm = blockIdx.y * 32;
    int fr = lane & 15, kb = lane >> 4;
    int q = kb, cl = fr;

    const unsigned short* gB1[4];
    const unsigned short* gB2[4];
    int dstB[4];
#pragma unroll
    for (int i = 0; i < 4; ++i) {
        int sB = i * 256 + tid;
        int r = sB >> 2, ck = (sB & 3) ^ ((r >> 1) & 3);
        gB1[i] = w1 + (size_t)(c * 256 + r) * 256 + ck * 8;
        gB2[i] = w2 + (size_t)r * 1024 + c * 256 + ck * 8;
        dstB[i] = sB * 8;
    }
    const unsigned short* gA = nullptr;
    if (tid < 128) {
        int ar = tid >> 2, ack = (tid & 3) ^ ((ar >> 1) & 3);
        gA = h1bf + (size_t)(bm + ar) * 256 + ack * 8;
    }

    int oA1[2], oB[4];
#pragma unroll
    for (int t = 0; t < 2; ++t) {
        int m = t * 16 + fr;
        oA1[t] = m * 32 + ((kb ^ ((m >> 1) & 3)) * 8);
    }
#pragma unroll
    for (int t = 0; t < 4; ++t) {
        int n = wave * 64 + t * 16 + fr;
        oB[t] = n * 32 + ((kb ^ ((n >> 1) & 3)) * 8);
    }

    auto stage1 = [&](int s, int dd) {
#pragma unroll
        for (int i = 0; i < 4; ++i) gload_lds16(gB1[i] + s * 32, &Bs[dd][dstB[i]]);
        if (tid < 128) gload_lds16(gA + s * 32, &As[dd][tid * 8]);
    };
    auto stage2 = [&](int s, int dd) {
#pragma unroll
        for (int i = 0; i < 4; ++i) gload_lds16(gB2[i] + s * 32, &Bs[dd][dstB[i]]);
    };

    f32x4 a1[2][4];
#pragma unroll
    for (int i = 0; i < 2; ++i)
#pragma unroll
        for (int j = 0; j < 4; ++j) a1[i][j] = (f32x4){0.f, 0.f, 0.f, 0.f};

    stage1(0, 0);
    __syncthreads();
    for (int ks = 0; ks < 8; ++ks) {
        int dd = ks & 1;
        if (ks + 1 < 8) stage1(ks + 1, dd ^ 1);
        bf16x8 af[2], bfv[4];
#pragma unroll
        for (int t = 0; t < 2; ++t) af[t] = *(const bf16x8*)&As[dd][oA1[t]];
#pragma unroll
        for (int t = 0; t < 4; ++t) bfv[t] = *(const bf16x8*)&Bs[dd][oB[t]];
#pragma unroll
        for (int i = 0; i < 2; ++i)
#pragma unroll
            for (int j = 0; j < 4; ++j)
                a1[i][j] = __builtin_amdgcn_mfma_f32_16x16x32_bf16(af[i], bfv[j], a1[i][j], 0, 0, 0);
        __syncthreads();
    }

#pragma unroll
    for (int ct = 0; ct < 4; ++ct) {
        int col = wave * 64 + ct * 16 + cl;
        float bj = f1b[c * 256 + col];
#pragma unroll
        for (int rt = 0; rt < 2; ++rt)
#pragma unroll
            for (int r = 0; r < 4; ++r) {
                float v = fmaxf(a1[rt][ct][r] + bj, 0.f);
                ffs[(rt * 16 + q * 4 + r) * 264 + col] = f2bf(v);
            }
    }

    f32x4 a2[2][4];
#pragma unroll
    for (int i = 0; i < 2; ++i)
#pragma unroll
        for (int j = 0; j < 4; ++j) a2[i][j] = (f32x4){0.f, 0.f, 0.f, 0.f};

    stage2(0, 0);
    __syncthreads();
    for (int ks = 0; ks < 8; ++ks) {
        int dd = ks & 1;
        if (ks + 1 < 8) stage2(ks + 1, dd ^ 1);
        bf16x8 af[2], bfv[4];
#pragma unroll
        for (int t = 0; t < 2; ++t)
            af[t] = *(const bf16x8*)&ffs[(t * 16 + fr) * 264 + ks * 32 + kb * 8];
#pragma unroll
        for (int t = 0; t < 4; ++t) bfv[t] = *(const bf16x8*)&Bs[dd][oB[t]];
#pragma unroll
        for (int i = 0; i < 2; ++i)
#pragma unroll
            for (int j = 0; j < 4; ++j)
                a2[i][j] = __builtin_amdgcn_mfma_f32_16x16x32_bf16(af[i], bfv[j], a2[i][j], 0, 0, 0);
        __syncthreads();
    }

#pragma unroll
    for (int ct = 0; ct < 4; ++ct) {
        int col = wave * 64 + ct * 16 + cl;
#pragma unroll
        for (int rt = 0; rt < 2; ++rt)
#pragma unroll
            for (int r = 0; r < 4; ++r)
                part[((size_t)c * 4096 + bm + rt * 16 + q * 4 + r) * 256 + col] = a2[rt][ct][r];
    }
}

// ---------------------------------------------------------------------------
// Kernel 6: merge FFN2 partials + bias + h1 residual + LN2 (+final fold).
// ---------------------------------------------------------------------------
__global__ __launch_bounds__(256) void merge_ln2(
    const float* __restrict__ h1, const float* __restrict__ part,
    const float* __restrict__ f2b, const float* __restrict__ g2,
    const float* __restrict__ bt2,
    float* __restrict__ hout, unsigned short* __restrict__ hbf,
    const float* __restrict__ outW, const float* __restrict__ outb,
    float* __restrict__ out, int doFinal,
    float* __restrict__ hts1, int doHts)
{
    __shared__ float red[4][256];

    int wrp = threadIdx.x >> 6;
    int row = blockIdx.x * 4 + wrp;
    int lane = threadIdx.x & 63;
    int d = lane * 4;

    float4 z = *(const float4*)(h1 + (size_t)row * 256 + d);
    float4 b4 = *(const float4*)(f2b + d);
    z.x += b4.x; z.y += b4.y; z.z += b4.z; z.w += b4.w;
#pragma unroll
    for (int c = 0; c < 4; ++c) {
        float4 p = *(const float4*)(part + ((size_t)c * 4096 + row) * 256 + d);
        z.x += p.x; z.y += p.y; z.z += p.z; z.w += p.w;
    }

    float s = z.x + z.y + z.z + z.w;
    float ss = z.x * z.x + z.y * z.y + z.z * z.z + z.w * z.w;
#pragma unroll
    for (int off = 1; off < 64; off <<= 1) {
        s += __shfl_xor(s, off);
        ss += __shfl_xor(ss, off);
    }
    float mean = s * (1.f / 256.f);
    float var = ss * (1.f / 256.f) - mean * mean;
    float inv = rsqrtf(var + 1e-5f);

    float4 g4 = *(const float4*)(g2 + d);
    float4 t4 = *(const float4*)(bt2 + d);
    float4 o;
    o.x = (z.x - mean) * inv * g4.x + t4.x;
    o.y = (z.y - mean) * inv * g4.y + t4.y;
    o.z = (z.z - mean) * inv * g4.z + t4.z;
    o.w = (z.w - mean) * inv * g4.w + t4.w;
    *(float4*)(hout + (size_t)row * 256 + d) = o;
    unsigned short s0 = f2bf(o.x), s1 = f2bf(o.y), s2 = f2bf(o.z), s3 = f2bf(o.w);
    unsigned int u01 = (unsigned)s0 | ((unsigned)s1 << 16);
    unsigned int u23 = (unsigned)s2 | ((unsigned)s3 << 16);
    *(uint2*)&hbf[(size_t)row * 256 + d] = make_uint2(u01, u23);

    if (doHts) {
        *(float4*)&red[wrp][d] = make_float4(bf2f(s0), bf2f(s1), bf2f(s2), bf2f(s3));
        __syncthreads();
        int cidx = threadIdx.x;
        float cs = red[0][cidx] + red[1][cidx] + red[2][cidx] + red[3][cidx];
        int b = blockIdx.x >> 9;
        int tile = (blockIdx.x >> 3) & 63;
        atomicAdd(&hts1[((b << 6) + tile) * 256 + cidx], cs);
    }

    if (doFinal && (row == 2047 || row == 4095)) {
        float4 w4 = *(const float4*)(outW + d);
        float s2f = o.x * w4.x + o.y * w4.y + o.z * w4.z + o.w * w4.w;
#pragma unroll
        for (int off = 1; off < 64; off <<= 1) s2f += __shfl_xor(s2f, off);
        if (lane == 0) out[row >> 11] = s2f * 0.5f + outb[0];
    }
}

// ---------------------------------------------------------------------------
extern "C" void kernel_launch(void* const* d_in, const int* in_sizes, int n_in,
                              void* d_out, int out_size, void* d_ws, size_t ws_size,
                              hipStream_t stream)
{
    (void)in_sizes; (void)n_in; (void)out_size; (void)ws_size;
    const float* x      = (const float*)d_in[0];
    const float* conv_w = (const float*)d_in[1];
    const float* conv_b = (const float*)d_in[2];
    const float* bn_g   = (const float*)d_in[3];
    const float* bn_b   = (const float*)d_in[4];
    const float* pe     = (const float*)d_in[5];
    const float* qW     = (const float*)d_in[6];
    const float* qb     = (const float*)d_in[7];
    const float* kW     = (const float*)d_in[8];
    const float* kb     = (const float*)d_in[9];
    const float* vW     = (const float*)d_in[10];
    const float* vb     = (const float*)d_in[11];
    const float* oW     = (const float*)d_in[12];
    const float* ob     = (const float*)d_in[13];
    const float* scale  = (const float*)d_in[14];
    const float* td     = (const float*)d_in[15];
    const float* ln1g   = (const float*)d_in[16];
    const float* ln1b   = (const float*)d_in[17];
    const float* f1W    = (const float*)d_in[18];
    const float* f1b    = (const float*)d_in[19];
    const float* f2W    = (const float*)d_in[20];
    const float* f2b    = (const float*)d_in[21];
    const float* ln2g   = (const float*)d_in[22];
    const float* ln2b   = (const float*)d_in[23];
    const float* outW   = (const float*)d_in[24];
    const float* outb   = (const float*)d_in[25];
    float* out = (float*)d_out;

    float* ws = (float*)d_ws;
    const size_t MT = (size_t)B_ * SEQ_ * D_;      // 1,048,576
    const size_t HTS = (size_t)B_ * 64 * 256;      // 32,768
    float* h     = ws;                             // MT fp32
    float* h1    = ws + MT;                        // MT fp32
    float* part  = ws + 2 * MT;                    // 4*MT fp32
    float* hts0  = ws + 6 * MT;                    // 32768 fp32
    float* hts1  = hts0 + HTS;                     // 32768 fp32
    float* vts_g = hts1 + HTS;                     // 512 fp32
    unsigned short* bfb = (unsigned short*)(vts_g + 512);
    unsigned short* h_bf   = bfb;
    unsigned short* ctx_bf = bfb + MT;
    unsigned short* q_bf   = bfb + 2 * MT;
    unsigned short* k_bf   = bfb + 3 * MT;
    unsigned short* v_bf   = bfb + 4 * MT;
    unsigned short* h1_bf  = bfb + 5 * MT;
    unsigned short* wq_bf  = bfb + 6 * MT;
    unsigned short* wk_bf  = wq_bf + MT / 8;
    unsigned short* wv_bf  = wk_bf + MT / 8;
    unsigned short* wo_bf  = wv_bf + MT / 8;
    unsigned short* wf1_bf = wo_bf + MT / 8;
    unsigned short* wf2_bf = wf1_bf + MT / 2;

    const int Mrows = B_ * SEQ_;                   // 4096

    prep_kernel<<<768 + 128, 256, 0, stream>>>(
        x, conv_w, conv_b, bn_g, bn_b, pe, h, h_bf,
        qW, kW, vW, oW, f1W, f2W,
        wq_bf, wk_bf, wv_bf, wo_bf, wf1_bf, wf2_bf, hts0, hts1);

    for (int l = 0; l < L_; ++l) {
        const unsigned short* wq_l  = wq_bf  + (size_t)l * D_ * D_;
        const unsigned short* wk_l  = wk_bf  + (size_t)l * D_ * D_;
        const unsigned short* wv_l  = wv_bf  + (size_t)l * D_ * D_;
        const unsigned short* wo_l  = wo_bf  + (size_t)l * D_ * D_;
        const unsigned short* wf1_l = wf1_bf + (size_t)l * DFF_ * D_;
        const unsigned short* wf2_l = wf2_bf + (size_t)l * DFF_ * D_;
        const float* hts_l = (l == 0) ? hts0 : hts1;

        gemm_qkv<<<dim3(D_ / 64, Mrows / 64, 4), 256, 0, stream>>>(
            h_bf, wq_l, wk_l, wv_l, qb + l * D_, kb + l * D_, vb + l * D_,
            q_bf, k_bf, v_bf, td + l * H_, hts_l, vts_g, Mrows, D_, D_);

        attn_kernel<<<dim3(SEQ_ / 32, H_, B_), 128, 0, stream>>>(
            q_bf, k_bf, v_bf, vts_g, ctx_bf, scale + l, td + l * H_);

        oproj_ln1<<<Mrows / 16, 256, 0, stream>>>(
            ctx_bf, wo_l, ob + l * D_, h,
            ln1g + l * D_, ln1b + l * D_, h1, h1_bf);

        ffn_fused<<<dim3(4, Mrows / 32), 256, 0, stream>>>(
            h1_bf, wf1_l, f1b + l * DFF_, wf2_l, part);

        merge_ln2<<<Mrows / 4, 256, 0, stream>>>(
            h1, part, f2b + l * D_, ln2g + l * D_, ln2b + l * D_,
            h, h_bf, outW, outb, out, (l == L_ - 1) ? 1 : 0,
            hts1, (l == 0) ? 1 : 0);
    }
}

// Round 7
// 185.549 us; speedup vs baseline: 1.2887x; 1.1195x over previous
//
#include <hip/hip_runtime.h>
#include <math.h>

#define B_    2
#define SEQ_  2048
#define D_    256
#define H_    8
#define DK_   32
#define L_    2
#define DFF_  1024

#define TD_CUT 44.0f

typedef short  bf16x8 __attribute__((ext_vector_type(8)));
typedef float  f32x4  __attribute__((ext_vector_type(4)));

__device__ __forceinline__ int compute_kcut(float tdv) {
    int kcut = SEQ_;
    if (tdv > 1e-9f) {
        float kc = TD_CUT / tdv;
        kcut = (kc >= (float)SEQ_) ? SEQ_ : ((int)kc + 1);
    }
    int kcr = (kcut + 63) & ~63;          // 64-granular: whole K-tiles
    if (kcr > SEQ_) kcr = SEQ_;
    return kcr;
}

__device__ __forceinline__ unsigned short f2bf(float f) {
    unsigned int u = __float_as_uint(f);
    unsigned int r = u + 0x7FFFu + ((u >> 16) & 1u);   // RNE
    return (unsigned short)(r >> 16);
}
__device__ __forceinline__ float bf2f(unsigned short u) {
    return __uint_as_float(((unsigned int)u) << 16);
}
__device__ __forceinline__ float bflo(unsigned int u) {
    return __uint_as_float(u << 16);
}
__device__ __forceinline__ float bfhi(unsigned int u) {
    return __uint_as_float(u & 0xFFFF0000u);
}

__device__ __forceinline__ void gload_lds16(const unsigned short* g, unsigned short* l) {
    __builtin_amdgcn_global_load_lds(
        (const __attribute__((address_space(1))) unsigned int*)(const unsigned int*)g,
        (__attribute__((address_space(3))) unsigned int*)(unsigned int*)l,
        16, 0, 0);
}

// ---------------------------------------------------------------------------
// Kernel 1: prep = weight cvt (blocks 0..767) + conv/pe/hts0 (blocks 768..895).
// ---------------------------------------------------------------------------
__global__ __launch_bounds__(256) void prep_kernel(
    const float* __restrict__ x, const float* __restrict__ w,
    const float* __restrict__ cb, const float* __restrict__ bg,
    const float* __restrict__ bb, const float* __restrict__ pe,
    float* __restrict__ h, unsigned short* __restrict__ hbf,
    const float* __restrict__ p0, const float* __restrict__ p1,
    const float* __restrict__ p2, const float* __restrict__ p3,
    const float* __restrict__ p4, const float* __restrict__ p5,
    unsigned short* __restrict__ q0, unsigned short* __restrict__ q1,
    unsigned short* __restrict__ q2, unsigned short* __restrict__ q3,
    unsigned short* __restrict__ q4, unsigned short* __restrict__ q5,
    float* __restrict__ hts0, float* __restrict__ hts1)
{
    int bid = blockIdx.x;
    if (bid < 768) {                              // ---- cvt path
        int t = bid * 256 + threadIdx.x;
        const float* src; unsigned short* dst; int base;
        if (t < 65536) {
            int a = t >> 14;
            src = a == 0 ? p0 : a == 1 ? p1 : a == 2 ? p2 : p3;
            dst = a == 0 ? q0 : a == 1 ? q1 : a == 2 ? q2 : q3;
            base = (t & 16383) * 8;
        } else {
            int u = t - 65536;
            int a = u >> 16;
            src = a ? p5 : p4;
            dst = a ? q5 : q4;
            base = (u & 65535) * 8;
        }
        float4 v0 = *(const float4*)(src + base);
        float4 v1 = *(const float4*)(src + base + 4);
        bf16x8 o;
        o[0] = (short)f2bf(v0.x); o[1] = (short)f2bf(v0.y);
        o[2] = (short)f2bf(v0.z); o[3] = (short)f2bf(v0.w);
        o[4] = (short)f2bf(v1.x); o[5] = (short)f2bf(v1.y);
        o[6] = (short)f2bf(v1.z); o[7] = (short)f2bf(v1.w);
        *(bf16x8*)(dst + base) = o;
        return;
    }
    // ---- conv path: block = (b, tile of 32 rows); thread = column d
    int bid2 = bid - 768;                         // 0..127
    int b    = bid2 >> 6;
    int tile = bid2 & 63;
    int d    = threadIdx.x;

    hts1[bid2 * 256 + d] = 0.f;

    const float* xp = x + b * SEQ_;
    float w0 = w[d * 3 + 0], w1v = w[d * 3 + 1], w2v = w[d * 3 + 2];
    float gg  = rsqrtf(1.f + 1e-5f) * bg[d];
    float cbd = cb[d], bbd = bb[d];

    int s0 = tile * 32;
    float xm1 = (s0 > 0) ? xp[s0 - 1] : 0.f;
    float x0v = xp[s0];
    float hsum = 0.f;
#pragma unroll 4
    for (int r = 0; r < 32; ++r) {
        int s = s0 + r;
        float xp1 = (s < SEQ_ - 1) ? xp[s + 1] : 0.f;
        float acc = xm1 * w0 + x0v * w1v + xp1 * w2v + cbd;
        acc = acc * gg + bbd;
        acc = fmaxf(acc, 0.f);
        float v = acc + pe[s * D_ + d];
        size_t idx = ((size_t)(b * SEQ_ + s)) * D_ + d;
        h[idx] = v;
        unsigned short ub = f2bf(v);
        hbf[idx] = ub;
        hsum += bf2f(ub);
        xm1 = x0v; x0v = xp1;
    }
    hts0[(b * 64 + tile) * 256 + d] = hsum;
}

// ---------------------------------------------------------------------------
// Kernel 2: q/k/v GEMM (bf16 in/out), BK=64 double-buffered pipeline.
// z==3 slice: vtail precompute — vts_g[b][h][32] from hts suffix-sum . Wv.
// K/V blocks (z==1,2) with rows >= kcut exit immediately.
// ---------------------------------------------------------------------------
__global__ __launch_bounds__(256) void gemm_qkv(
    const unsigned short* __restrict__ A,
    const unsigned short* __restrict__ W0, const unsigned short* __restrict__ W1,
    const unsigned short* __restrict__ W2,
    const float* __restrict__ b0, const float* __restrict__ b1,
    const float* __restrict__ b2,
    unsigned short* __restrict__ O0, unsigned short* __restrict__ O1,
    unsigned short* __restrict__ O2,
    const float* __restrict__ td_l,
    const float* __restrict__ hts_l, float* __restrict__ vts_g,
    int M, int N, int K)
{
    __shared__ unsigned short As[2][2][2048];     // [buf][k-slab][64x32]
    __shared__ unsigned short Bs[2][2][2048];
    __shared__ float hsc[256];

    int z = blockIdx.z;
    int tid  = threadIdx.x;

    if (z == 3) {                                 // ---- vtail path
        if (blockIdx.x != 0 || blockIdx.y >= 16) return;
        int hh = blockIdx.y & 7;
        int b  = blockIdx.y >> 3;
        int kcr = compute_kcut(td_l[hh]);
        if (kcr >= SEQ_) return;                  // no tail needed
        int tcut = kcr >> 5;                      // 32-row tile units (even)
        // Phase A: masked suffix column-sum over 64 tiles (fully unrolled)
        const float* hb = hts_l + (size_t)b * 64 * 256 + tid;
        float s = 0.f;
#pragma unroll
        for (int t = 0; t < 64; ++t) {
            float v = hb[t * 256];
            s += (t >= tcut) ? v : 0.f;
        }
        hsc[tid] = s;
        __syncthreads();
        // Phase B: vts[j] = hsc . Wv[hh*32+j] + (SEQ-kcr)*vb
        int j = tid >> 3, e = tid & 7;
        const unsigned short* wrow = W2 + (size_t)(hh * 32 + j) * 256 + e * 32;
        float dot = 0.f;
#pragma unroll
        for (int i = 0; i < 4; ++i) {
            bf16x8 w8 = *(const bf16x8*)(wrow + i * 8);
#pragma unroll
            for (int t2 = 0; t2 < 8; ++t2)
                dot += hsc[e * 32 + i * 8 + t2] * bf2f((unsigned short)w8[t2]);
        }
        dot += __shfl_xor(dot, 1);
        dot += __shfl_xor(dot, 2);
        dot += __shfl_xor(dot, 4);
        if (e == 0)
            vts_g[(b * H_ + hh) * 32 + j] = dot + (float)(SEQ_ - kcr) * b2[hh * 32 + j];
        return;
    }

    int bm = blockIdx.y * 64, bn = blockIdx.x * 64;
    if (z > 0) {
        float tdmin = td_l[0];
#pragma unroll
        for (int i = 1; i < H_; ++i) tdmin = fminf(tdmin, td_l[i]);
        if ((bm & (SEQ_ - 1)) >= compute_kcut(tdmin)) return;   // block-uniform
    }
    const unsigned short* W = (z == 0) ? W0 : (z == 1) ? W1 : W2;
    const float* bias = (z == 0) ? b0 : (z == 1) ? b1 : b2;
    unsigned short* C = (z == 0) ? O0 : (z == 1) ? O1 : O2;

    int wave = tid >> 6, lane = tid & 63;
    int wm = (wave & 1) * 32, wn = (wave >> 1) * 32;

    int sr  = tid >> 2;
    int scb = (tid & 3) ^ ((sr >> 1) & 3);
    const unsigned short* aG = A + (size_t)(bm + sr) * K + scb * 8;
    const unsigned short* wG = W + (size_t)(bn + sr) * K + scb * 8;

    int fr = lane & 15;
    int kb = lane >> 4;
    int cbo = (kb ^ ((fr >> 1) & 3)) * 8;
    int oA0 = (wm + fr) * 32 + cbo;
    int oA1 = (wm + 16 + fr) * 32 + cbo;
    int oB0 = (wn + fr) * 32 + cbo;
    int oB1 = (wn + 16 + fr) * 32 + cbo;

    f32x4 acc[2][2];
#pragma unroll
    for (int i = 0; i < 2; ++i)
#pragma unroll
        for (int j = 0; j < 2; ++j) acc[i][j] = (f32x4){0.f, 0.f, 0.f, 0.f};

    auto stage = [&](int s, int dd) {
        gload_lds16(aG + s * 64,      &As[dd][0][tid * 8]);
        gload_lds16(aG + s * 64 + 32, &As[dd][1][tid * 8]);
        gload_lds16(wG + s * 64,      &Bs[dd][0][tid * 8]);
        gload_lds16(wG + s * 64 + 32, &Bs[dd][1][tid * 8]);
    };

    int nst = K >> 6;                              // 4 steps (BK=64)
    stage(0, 0);
    __syncthreads();
    for (int s = 0; s < nst; ++s) {
        int dd = s & 1;
        if (s + 1 < nst) stage(s + 1, dd ^ 1);
#pragma unroll
        for (int kk = 0; kk < 2; ++kk) {
            bf16x8 a0f = *(const bf16x8*)&As[dd][kk][oA0];
            bf16x8 a1f = *(const bf16x8*)&As[dd][kk][oA1];
            bf16x8 b0f = *(const bf16x8*)&Bs[dd][kk][oB0];
            bf16x8 b1f = *(const bf16x8*)&Bs[dd][kk][oB1];
            acc[0][0] = __builtin_amdgcn_mfma_f32_16x16x32_bf16(a0f, b0f, acc[0][0], 0, 0, 0);
            acc[0][1] = __builtin_amdgcn_mfma_f32_16x16x32_bf16(a0f, b1f, acc[0][1], 0, 0, 0);
            acc[1][0] = __builtin_amdgcn_mfma_f32_16x16x32_bf16(a1f, b0f, acc[1][0], 0, 0, 0);
            acc[1][1] = __builtin_amdgcn_mfma_f32_16x16x32_bf16(a1f, b1f, acc[1][1], 0, 0, 0);
        }
        __syncthreads();
    }

    int crow = (lane >> 4) * 4;
    int ccol = lane & 15;
#pragma unroll
    for (int j = 0; j < 2; ++j) {
        float bj = bias[bn + wn + j * 16 + ccol];
#pragma unroll
        for (int i = 0; i < 2; ++i) {
#pragma unroll
            for (int r = 0; r < 4; ++r) {
                float v = acc[i][j][r] + bj;
                C[(size_t)(bm + wm + i * 16 + crow + r) * N + bn + wn + j * 16 + ccol] = f2bf(v);
            }
        }
    }
}

// ---------------------------------------------------------------------------
// Kernel 3: MFMA flash attention. Block = (b, h, 64 q-rows), 4 waves; wave w
// owns q-rows w*16..w*16+15 and all 64 keys of each tile. Fixed-0 softmax
// shift (tail guarantees the reference) => softmax is elementwise; l is a
// per-lane partial reduced by 4 shfl_xor at the end. QK^T and PV via
// mfma_16x16x32 (fragment layouts identical to the proven gemm_qkv).
// V staged transposed (vtT[dim][key]) so PV B-frags are contiguous 16B.
// Tail: l += SEQ-kcr, O += 0.5*vts (vts precomputed by gemm z==3).
// ---------------------------------------------------------------------------
__global__ __launch_bounds__(256) void attn_kernel(
    const unsigned short* __restrict__ q, const unsigned short* __restrict__ k,
    const unsigned short* __restrict__ v, const float* __restrict__ vts_g,
    unsigned short* __restrict__ ctxbf,
    const float* __restrict__ scale_p, const float* __restrict__ td_l)
{
    int b = blockIdx.z, hh = blockIdx.y;
    int tid = threadIdx.x;
    int wave = tid >> 6, lane = tid & 63;
    int q0r = blockIdx.x * 64;

    float sc  = 0.17677669529663687f * scale_p[0];
    float tdv = td_l[hh];
    int kcr = compute_kcut(tdv);                  // block-uniform, 64-granular
    int ntiles = kcr >> 6;                        // 64-key tiles (>=1)

    __shared__ unsigned short qt[64 * 32];        // [qrow][dim]
    __shared__ unsigned short kt[64 * 32];        // [key][dim]
    __shared__ unsigned short vtT[32 * 72];       // [dim][key], padded stride 72
    __shared__ unsigned short pl[64 * 72];        // [qrow][key], padded stride 72
    __shared__ float vts_s[32];

    if (tid < 32) vts_s[tid] = vts_g[(b * H_ + hh) * 32 + tid];

    int srow = tid >> 2, sseg = tid & 3;          // staging: row, 16B segment
    // stage Q once (LDS dest = wave-uniform base + lane*16)
    gload_lds16(q + ((size_t)(b * SEQ_ + q0r + srow)) * D_ + hh * DK_ + sseg * 8,
                &qt[tid * 8]);

    int fr = lane & 15, kb = lane >> 4;
    const unsigned short* qfrag = &qt[(wave * 16 + fr) * 32 + kb * 8];

    f32x4 acc_o[2];
    acc_o[0] = (f32x4){0.f, 0.f, 0.f, 0.f};
    acc_o[1] = (f32x4){0.f, 0.f, 0.f, 0.f};
    float lpart[4] = {0.f, 0.f, 0.f, 0.f};

    for (int t = 0; t < ntiles; ++t) {
        int k0 = t * 64;
        if (t > 0) __syncthreads();               // WAR: prior tile's reads done
        {
            gload_lds16(k + ((size_t)(b * SEQ_ + k0 + srow)) * D_ + hh * DK_ + sseg * 8,
                        &kt[tid * 8]);
            // V transposed: reg-stage 8 bf16 of v[row][d0..d0+7] -> vtT[d][row]
            const unsigned short* vp =
                v + ((size_t)(b * SEQ_ + k0 + srow)) * D_ + hh * DK_ + sseg * 8;
            uint4 uv = *(const uint4*)vp;
            unsigned short ve[8];
            ve[0] = (unsigned short)(uv.x); ve[1] = (unsigned short)(uv.x >> 16);
            ve[2] = (unsigned short)(uv.y); ve[3] = (unsigned short)(uv.y >> 16);
            ve[4] = (unsigned short)(uv.z); ve[5] = (unsigned short)(uv.z >> 16);
            ve[6] = (unsigned short)(uv.w); ve[7] = (unsigned short)(uv.w >> 16);
#pragma unroll
            for (int e = 0; e < 8; ++e)
                vtT[(sseg * 8 + e) * 72 + srow] = ve[e];
        }
        __syncthreads();                          // staging visible (vmcnt+lgkm drained)

        // ---- S = Q·K^T : wave's 16 q-rows x 64 keys (4 key-tiles, K=32)
        f32x4 acc_s[4];
        bf16x8 aq = *(const bf16x8*)qfrag;
#pragma unroll
        for (int kt_i = 0; kt_i < 4; ++kt_i) {
            bf16x8 bk = *(const bf16x8*)&kt[(kt_i * 16 + fr) * 32 + kb * 8];
            acc_s[kt_i] = __builtin_amdgcn_mfma_f32_16x16x32_bf16(
                aq, bk, (f32x4){0.f, 0.f, 0.f, 0.f}, 0, 0, 0);
        }
        // ---- elementwise softmax (shift 0) + decay; P -> LDS
#pragma unroll
        for (int kt_i = 0; kt_i < 4; ++kt_i) {
#pragma unroll
            for (int r = 0; r < 4; ++r) {
                int key = k0 + kt_i * 16 + fr;
                float sv = acc_s[kt_i][r] * sc * __expf(-tdv * (float)key);
                float e  = __expf(sv);
                float sg = 1.f / (1.f + __expf(-sv));
                lpart[r] += e;
                int qrow = wave * 16 + kb * 4 + r;
                pl[qrow * 72 + kt_i * 16 + fr] = f2bf(e * sg);
            }
        }
        __syncthreads();                          // publish P

        // ---- O += P·V (K=64 over 2 k-steps; dims in 2 n-tiles)
#pragma unroll
        for (int ks = 0; ks < 2; ++ks) {
            bf16x8 pa = *(const bf16x8*)&pl[(wave * 16 + fr) * 72 + ks * 32 + kb * 8];
#pragma unroll
            for (int nt = 0; nt < 2; ++nt) {
                bf16x8 vb8 = *(const bf16x8*)&vtT[(nt * 16 + fr) * 72 + ks * 32 + kb * 8];
                acc_o[nt] = __builtin_amdgcn_mfma_f32_16x16x32_bf16(pa, vb8, acc_o[nt], 0, 0, 0);
            }
        }
    }

    // ---- reduce l across the 16 lanes sharing each q-row
#pragma unroll
    for (int r = 0; r < 4; ++r) {
        lpart[r] += __shfl_xor(lpart[r], 1);
        lpart[r] += __shfl_xor(lpart[r], 2);
        lpart[r] += __shfl_xor(lpart[r], 4);
        lpart[r] += __shfl_xor(lpart[r], 8);
    }
    float taill = (kcr < SEQ_) ? (float)(SEQ_ - kcr) : 0.f;

    // ---- epilogue: tail add, normalize, write ctx (2B stores, 32B segments)
#pragma unroll
    for (int nt = 0; nt < 2; ++nt) {
        float vadd = (kcr < SEQ_) ? 0.5f * vts_s[nt * 16 + fr] : 0.f;
#pragma unroll
        for (int r = 0; r < 4; ++r) {
            float invL = 1.f / (lpart[r] + taill);
            float o = (acc_o[nt][r] + vadd) * invL;
            int qrow = q0r + wave * 16 + kb * 4 + r;
            ctxbf[((size_t)(b * SEQ_ + qrow)) * D_ + hh * DK_ + nt * 16 + fr] = f2bf(o);
        }
    }
}

// ---------------------------------------------------------------------------
// Kernel 4: o-proj + residual + LN1. 16 rows x 256 cols per block.
// ---------------------------------------------------------------------------
__global__ __launch_bounds__(256) void oproj_ln1(
    const unsigned short* __restrict__ ctx, const unsigned short* __restrict__ wo,
    const float* __restrict__ ob, const float* __restrict__ resid,
    const float* __restrict__ g1, const float* __restrict__ bt1,
    float* __restrict__ h1out, unsigned short* __restrict__ h1bf)
{
    __shared__ unsigned short As[2][512];
    __shared__ unsigned short Bs[2][8192];
    __shared__ float lsum[4][16], lsq[4][16], mean_s[16], inv_s[16];

    int tid = threadIdx.x;
    int wave = tid >> 6, lane = tid & 63;
    int bm = blockIdx.x * 16;
    int fr = lane & 15, kb = lane >> 4;
    int q = kb, cl = fr;
    int swz = (fr >> 1) & 3;

    const unsigned short* gpB[4];
    int dstB[4];
#pragma unroll
    for (int i = 0; i < 4; ++i) {
        int sB = i * 256 + tid;
        int r = sB >> 2, ck = (sB & 3) ^ ((r >> 1) & 3);
        gpB[i] = wo + (size_t)r * 256 + ck * 8;
        dstB[i] = sB * 8;
    }
    const unsigned short* gpA = nullptr;
    if (tid < 64) {
        int r = tid >> 2, ck = (tid & 3) ^ ((r >> 1) & 3);
        gpA = ctx + (size_t)(bm + r) * 256 + ck * 8;
    }

    int oA = fr * 32 + ((kb ^ swz) * 8);
    int oB[4];
#pragma unroll
    for (int t = 0; t < 4; ++t) {
        int n = wave * 64 + t * 16 + fr;
        oB[t] = n * 32 + ((kb ^ swz) * 8);
    }

    f32x4 acc[4];
#pragma unroll
    for (int j = 0; j < 4; ++j) acc[j] = (f32x4){0.f, 0.f, 0.f, 0.f};

    auto stage = [&](int s, int dd) {
#pragma unroll
        for (int i = 0; i < 4; ++i) gload_lds16(gpB[i] + s * 32, &Bs[dd][dstB[i]]);
        if (tid < 64) gload_lds16(gpA + s * 32, &As[dd][tid * 8]);
    };

    stage(0, 0);
    __syncthreads();
    for (int s = 0; s < 8; ++s) {
        int dd = s & 1;
        if (s + 1 < 8) stage(s + 1, dd ^ 1);
        bf16x8 af = *(const bf16x8*)&As[dd][oA];
#pragma unroll
        for (int j = 0; j < 4; ++j)
            acc[j] = __builtin_amdgcn_mfma_f32_16x16x32_bf16(
                af, *(const bf16x8*)&Bs[dd][oB[j]], acc[j], 0, 0, 0);
        __syncthreads();
    }

    float zsum[4] = {0.f, 0.f, 0.f, 0.f}, zsq[4] = {0.f, 0.f, 0.f, 0.f};
    float zv[4][4];
#pragma unroll
    for (int ct = 0; ct < 4; ++ct) {
        int col = wave * 64 + ct * 16 + cl;
        float bj = ob[col];
#pragma unroll
        for (int r = 0; r < 4; ++r) {
            int row = bm + q * 4 + r;
            float z = acc[ct][r] + bj + resid[(size_t)row * 256 + col];
            zv[ct][r] = z;
            zsum[r] += z;
            zsq[r]  += z * z;
        }
    }
#pragma unroll
    for (int r = 0; r < 4; ++r) {
#pragma unroll
        for (int off = 1; off < 16; off <<= 1) {
            zsum[r] += __shfl_xor(zsum[r], off);
            zsq[r]  += __shfl_xor(zsq[r], off);
        }
    }
    if (cl == 0) {
#pragma unroll
        for (int r = 0; r < 4; ++r) {
            lsum[wave][q * 4 + r] = zsum[r];
            lsq[wave][q * 4 + r]  = zsq[r];
        }
    }
    __syncthreads();
    if (tid < 16) {
        float s  = lsum[0][tid] + lsum[1][tid] + lsum[2][tid] + lsum[3][tid];
        float sq = lsq[0][tid] + lsq[1][tid] + lsq[2][tid] + lsq[3][tid];
        float mean = s * (1.f / 256.f);
        float var  = sq * (1.f / 256.f) - mean * mean;
        mean_s[tid] = mean;
        inv_s[tid]  = rsqrtf(var + 1e-5f);
    }
    __syncthreads();

#pragma unroll
    for (int ct = 0; ct < 4; ++ct) {
        int col = wave * 64 + ct * 16 + cl;
        float gc = g1[col], bc = bt1[col];
#pragma unroll
        for (int r = 0; r < 4; ++r) {
            int lr = q * 4 + r;
            float o = (zv[ct][r] - mean_s[lr]) * inv_s[lr] * gc + bc;
            size_t off = (size_t)(bm + lr) * 256 + col;
            h1out[off] = o;
            h1bf[off]  = f2bf(o);
        }
    }
}

// ---------------------------------------------------------------------------
// Kernel 5: fused FFN chunk, double-buffered staging in both phases.
// ---------------------------------------------------------------------------
__global__ __launch_bounds__(256) void ffn_fused(
    const unsigned short* __restrict__ h1bf, const unsigned short* __restrict__ w1,
    const float* __restrict__ f1b, const unsigned short* __restrict__ w2,
    float* __restrict__ part)
{
    __shared__ unsigned short As[2][1024];
    __shared__ unsigned short Bs[2][8192];
    __shared__ unsigned short ffs[32 * 264];

    int tid = threadIdx.x;
    int wave = tid >> 6, lane = tid & 63;
    int c = blockIdx.x;
    int bm = blockIdx.y * 32;
    int fr = lane & 15, kb = lane >> 4;
    int q = kb, cl = fr;

    const unsigned short* gB1[4];
    const unsigned short* gB2[4];
    int dstB[4];
#pragma unroll
    for (int i = 0; i < 4; ++i) {
        int sB = i * 256 + tid;
        int r = sB >> 2, ck = (sB & 3) ^ ((r >> 1) & 3);
        gB1[i] = w1 + (size_t)(c * 256 + r) * 256 + ck * 8;
        gB2[i] = w2 + (size_t)r * 1024 + c * 256 + ck * 8;
        dstB[i] = sB * 8;
    }
    const unsigned short* gA = nullptr;
    if (tid < 128) {
        int ar = tid >> 2, ack = (tid & 3) ^ ((ar >> 1) & 3);
        gA = h1bf + (size_t)(bm + ar) * 256 + ack * 8;
    }

    int oA1[2], oB[4];
#pragma unroll
    for (int t = 0; t < 2; ++t) {
        int m = t * 16 + fr;
        oA1[t] = m * 32 + ((kb ^ ((m >> 1) & 3)) * 8);
    }
#pragma unroll
    for (int t = 0; t < 4; ++t) {
        int n = wave * 64 + t * 16 + fr;
        oB[t] = n * 32 + ((kb ^ ((n >> 1) & 3)) * 8);
    }

    auto stage1 = [&](int s, int dd) {
#pragma unroll
        for (int i = 0; i < 4; ++i) gload_lds16(gB1[i] + s * 32, &Bs[dd][dstB[i]]);
        if (tid < 128) gload_lds16(gA + s * 32, &As[dd][tid * 8]);
    };
    auto stage2 = [&](int s, int dd) {
#pragma unroll
        for (int i = 0; i < 4; ++i) gload_lds16(gB2[i] + s * 32, &Bs[dd][dstB[i]]);
    };

    f32x4 a1[2][4];
#pragma unroll
    for (int i = 0; i < 2; ++i)
#pragma unroll
        for (int j = 0; j < 4; ++j) a1[i][j] = (f32x4){0.f, 0.f, 0.f, 0.f};

    stage1(0, 0);
    __syncthreads();
    for (int ks = 0; ks < 8; ++ks) {
        int dd = ks & 1;
        if (ks + 1 < 8) stage1(ks + 1, dd ^ 1);
        bf16x8 af[2], bfv[4];
#pragma unroll
        for (int t = 0; t < 2; ++t) af[t] = *(const bf16x8*)&As[dd][oA1[t]];
#pragma unroll
        for (int t = 0; t < 4; ++t) bfv[t] = *(const bf16x8*)&Bs[dd][oB[t]];
#pragma unroll
        for (int i = 0; i < 2; ++i)
#pragma unroll
            for (int j = 0; j < 4; ++j)
                a1[i][j] = __builtin_amdgcn_mfma_f32_16x16x32_bf16(af[i], bfv[j], a1[i][j], 0, 0, 0);
        __syncthreads();
    }

#pragma unroll
    for (int ct = 0; ct < 4; ++ct) {
        int col = wave * 64 + ct * 16 + cl;
        float bj = f1b[c * 256 + col];
#pragma unroll
        for (int rt = 0; rt < 2; ++rt)
#pragma unroll
            for (int r = 0; r < 4; ++r) {
                float v = fmaxf(a1[rt][ct][r] + bj, 0.f);
                ffs[(rt * 16 + q * 4 + r) * 264 + col] = f2bf(v);
            }
    }

    f32x4 a2[2][4];
#pragma unroll
    for (int i = 0; i < 2; ++i)
#pragma unroll
        for (int j = 0; j < 4; ++j) a2[i][j] = (f32x4){0.f, 0.f, 0.f, 0.f};

    stage2(0, 0);
    __syncthreads();
    for (int ks = 0; ks < 8; ++ks) {
        int dd = ks & 1;
        if (ks + 1 < 8) stage2(ks + 1, dd ^ 1);
        bf16x8 af[2], bfv[4];
#pragma unroll
        for (int t = 0; t < 2; ++t)
            af[t] = *(const bf16x8*)&ffs[(t * 16 + fr) * 264 + ks * 32 + kb * 8];
#pragma unroll
        for (int t = 0; t < 4; ++t) bfv[t] = *(const bf16x8*)&Bs[dd][oB[t]];
#pragma unroll
        for (int i = 0; i < 2; ++i)
#pragma unroll
            for (int j = 0; j < 4; ++j)
                a2[i][j] = __builtin_amdgcn_mfma_f32_16x16x32_bf16(af[i], bfv[j], a2[i][j], 0, 0, 0);
        __syncthreads();
    }

#pragma unroll
    for (int ct = 0; ct < 4; ++ct) {
        int col = wave * 64 + ct * 16 + cl;
#pragma unroll
        for (int rt = 0; rt < 2; ++rt)
#pragma unroll
            for (int r = 0; r < 4; ++r)
                part[((size_t)c * 4096 + bm + rt * 16 + q * 4 + r) * 256 + col] = a2[rt][ct][r];
    }
}

// ---------------------------------------------------------------------------
// Kernel 6: merge FFN2 partials + bias + h1 residual + LN2 (+final fold).
// ---------------------------------------------------------------------------
__global__ __launch_bounds__(256) void merge_ln2(
    const float* __restrict__ h1, const float* __restrict__ part,
    const float* __restrict__ f2b, const float* __restrict__ g2,
    const float* __restrict__ bt2,
    float* __restrict__ hout, unsigned short* __restrict__ hbf,
    const float* __restrict__ outW, const float* __restrict__ outb,
    float* __restrict__ out, int doFinal,
    float* __restrict__ hts1, int doHts)
{
    __shared__ float red[4][256];

    int wrp = threadIdx.x >> 6;
    int row = blockIdx.x * 4 + wrp;
    int lane = threadIdx.x & 63;
    int d = lane * 4;

    float4 z = *(const float4*)(h1 + (size_t)row * 256 + d);
    float4 b4 = *(const float4*)(f2b + d);
    z.x += b4.x; z.y += b4.y; z.z += b4.z; z.w += b4.w;
#pragma unroll
    for (int c = 0; c < 4; ++c) {
        float4 p = *(const float4*)(part + ((size_t)c * 4096 + row) * 256 + d);
        z.x += p.x; z.y += p.y; z.z += p.z; z.w += p.w;
    }

    float s = z.x + z.y + z.z + z.w;
    float ss = z.x * z.x + z.y * z.y + z.z * z.z + z.w * z.w;
#pragma unroll
    for (int off = 1; off < 64; off <<= 1) {
        s += __shfl_xor(s, off);
        ss += __shfl_xor(ss, off);
    }
    float mean = s * (1.f / 256.f);
    float var = ss * (1.f / 256.f) - mean * mean;
    float inv = rsqrtf(var + 1e-5f);

    float4 g4 = *(const float4*)(g2 + d);
    float4 t4 = *(const float4*)(bt2 + d);
    float4 o;
    o.x = (z.x - mean) * inv * g4.x + t4.x;
    o.y = (z.y - mean) * inv * g4.y + t4.y;
    o.z = (z.z - mean) * inv * g4.z + t4.z;
    o.w = (z.w - mean) * inv * g4.w + t4.w;
    *(float4*)(hout + (size_t)row * 256 + d) = o;
    unsigned short s0 = f2bf(o.x), s1 = f2bf(o.y), s2 = f2bf(o.z), s3 = f2bf(o.w);
    unsigned int u01 = (unsigned)s0 | ((unsigned)s1 << 16);
    unsigned int u23 = (unsigned)s2 | ((unsigned)s3 << 16);
    *(uint2*)&hbf[(size_t)row * 256 + d] = make_uint2(u01, u23);

    if (doHts) {
        *(float4*)&red[wrp][d] = make_float4(bf2f(s0), bf2f(s1), bf2f(s2), bf2f(s3));
        __syncthreads();
        int cidx = threadIdx.x;
        float cs = red[0][cidx] + red[1][cidx] + red[2][cidx] + red[3][cidx];
        int b = blockIdx.x >> 9;
        int tile = (blockIdx.x >> 3) & 63;
        atomicAdd(&hts1[((b << 6) + tile) * 256 + cidx], cs);
    }

    if (doFinal && (row == 2047 || row == 4095)) {
        float4 w4 = *(const float4*)(outW + d);
        float s2f = o.x * w4.x + o.y * w4.y + o.z * w4.z + o.w * w4.w;
#pragma unroll
        for (int off = 1; off < 64; off <<= 1) s2f += __shfl_xor(s2f, off);
        if (lane == 0) out[row >> 11] = s2f * 0.5f + outb[0];
    }
}

// ---------------------------------------------------------------------------
extern "C" void kernel_launch(void* const* d_in, const int* in_sizes, int n_in,
                              void* d_out, int out_size, void* d_ws, size_t ws_size,
                              hipStream_t stream)
{
    (void)in_sizes; (void)n_in; (void)out_size; (void)ws_size;
    const float* x      = (const float*)d_in[0];
    const float* conv_w = (const float*)d_in[1];
    const float* conv_b = (const float*)d_in[2];
    const float* bn_g   = (const float*)d_in[3];
    const float* bn_b   = (const float*)d_in[4];
    const float* pe     = (const float*)d_in[5];
    const float* qW     = (const float*)d_in[6];
    const float* qb     = (const float*)d_in[7];
    const float* kW     = (const float*)d_in[8];
    const float* kb     = (const float*)d_in[9];
    const float* vW     = (const float*)d_in[10];
    const float* vb     = (const float*)d_in[11];
    const float* oW     = (const float*)d_in[12];
    const float* ob     = (const float*)d_in[13];
    const float* scale  = (const float*)d_in[14];
    const float* td     = (const float*)d_in[15];
    const float* ln1g   = (const float*)d_in[16];
    const float* ln1b   = (const float*)d_in[17];
    const float* f1W    = (const float*)d_in[18];
    const float* f1b    = (const float*)d_in[19];
    const float* f2W    = (const float*)d_in[20];
    const float* f2b    = (const float*)d_in[21];
    const float* ln2g   = (const float*)d_in[22];
    const float* ln2b   = (const float*)d_in[23];
    const float* outW   = (const float*)d_in[24];
    const float* outb   = (const float*)d_in[25];
    float* out = (float*)d_out;

    float* ws = (float*)d_ws;
    const size_t MT = (size_t)B_ * SEQ_ * D_;      // 1,048,576
    const size_t HTS = (size_t)B_ * 64 * 256;      // 32,768
    float* h     = ws;                             // MT fp32
    float* h1    = ws + MT;                        // MT fp32
    float* part  = ws + 2 * MT;                    // 4*MT fp32
    float* hts0  = ws + 6 * MT;                    // 32768 fp32
    float* hts1  = hts0 + HTS;                     // 32768 fp32
    float* vts_g = hts1 + HTS;                     // 512 fp32
    unsigned short* bfb = (unsigned short*)(vts_g + 512);
    unsigned short* h_bf   = bfb;
    unsigned short* ctx_bf = bfb + MT;
    unsigned short* q_bf   = bfb + 2 * MT;
    unsigned short* k_bf   = bfb + 3 * MT;
    unsigned short* v_bf   = bfb + 4 * MT;
    unsigned short* h1_bf  = bfb + 5 * MT;
    unsigned short* wq_bf  = bfb + 6 * MT;
    unsigned short* wk_bf  = wq_bf + MT / 8;
    unsigned short* wv_bf  = wk_bf + MT / 8;
    unsigned short* wo_bf  = wv_bf + MT / 8;
    unsigned short* wf1_bf = wo_bf + MT / 8;
    unsigned short* wf2_bf = wf1_bf + MT / 2;

    const int Mrows = B_ * SEQ_;                   // 4096

    prep_kernel<<<768 + 128, 256, 0, stream>>>(
        x, conv_w, conv_b, bn_g, bn_b, pe, h, h_bf,
        qW, kW, vW, oW, f1W, f2W,
        wq_bf, wk_bf, wv_bf, wo_bf, wf1_bf, wf2_bf, hts0, hts1);

    for (int l = 0; l < L_; ++l) {
        const unsigned short* wq_l  = wq_bf  + (size_t)l * D_ * D_;
        const unsigned short* wk_l  = wk_bf  + (size_t)l * D_ * D_;
        const unsigned short* wv_l  = wv_bf  + (size_t)l * D_ * D_;
        const unsigned short* wo_l  = wo_bf  + (size_t)l * D_ * D_;
        const unsigned short* wf1_l = wf1_bf + (size_t)l * DFF_ * D_;
        const unsigned short* wf2_l = wf2_bf + (size_t)l * DFF_ * D_;
        const float* hts_l = (l == 0) ? hts0 : hts1;

        gemm_qkv<<<dim3(D_ / 64, Mrows / 64, 4), 256, 0, stream>>>(
            h_bf, wq_l, wk_l, wv_l, qb + l * D_, kb + l * D_, vb + l * D_,
            q_bf, k_bf, v_bf, td + l * H_, hts_l, vts_g, Mrows, D_, D_);

        attn_kernel<<<dim3(SEQ_ / 64, H_, B_), 256, 0, stream>>>(
            q_bf, k_bf, v_bf, vts_g, ctx_bf, scale + l, td + l * H_);

        oproj_ln1<<<Mrows / 16, 256, 0, stream>>>(
            ctx_bf, wo_l, ob + l * D_, h,
            ln1g + l * D_, ln1b + l * D_, h1, h1_bf);

        ffn_fused<<<dim3(4, Mrows / 32), 256, 0, stream>>>(
            h1_bf, wf1_l, f1b + l * DFF_, wf2_l, part);

        merge_ln2<<<Mrows / 4, 256, 0, stream>>>(
            h1, part, f2b + l * D_, ln2g + l * D_, ln2b + l * D_,
            h, h_bf, outW, outb, out, (l == L_ - 1) ? 1 : 0,
            hts1, (l == 0) ? 1 : 0);
    }
}